// Round 8
// baseline (305.676 us; speedup 1.0000x reference)
//
#include <hip/hip_runtime.h>
#include <hip/hip_bf16.h>
#include <hip/hip_fp16.h>
#include <math.h>

#define SLOPE 0.2f

typedef __attribute__((ext_vector_type(8))) short bf16x8;
typedef __attribute__((ext_vector_type(4))) float f32x4;

// bf16 helpers (manual, RNE)
__device__ inline unsigned short f2bf(float f) {
    unsigned u = __float_as_uint(f);
    u += 0x7FFF + ((u >> 16) & 1);
    return (unsigned short)(u >> 16);
}
__device__ inline float bf2f(unsigned short s) {
    return __uint_as_float(((unsigned)s) << 16);
}

// ---------------- CSR build (separate dispatches; R6: coop grid.sync ~100us
// per barrier on MI355X -> NEVER use cooperative launch for this) ----------

// rank[i] = arrival order of edge i at its dst node (doubles as cursor pass).
__global__ void deg_kernel(const int* __restrict__ dst, int* __restrict__ deg,
                           int* __restrict__ rank, int E) {
    int i = blockIdx.x * blockDim.x + threadIdx.x;
    if (i < E) rank[i] = atomicAdd(&deg[dst[i]], 1);
}

// Two-level device-wide exclusive scan (N <= 65536 so nb <= 256).
__global__ __launch_bounds__(256) void psum_kernel(const int* __restrict__ deg,
                                                   int* __restrict__ bsum, int n) {
    const int t = threadIdx.x;
    const int i = blockIdx.x * 256 + t;
    int v = (i < n) ? deg[i] : 0;
#pragma unroll
    for (int o = 1; o < 64; o <<= 1) v += __shfl_xor(v, o, 64);
    __shared__ int ws[4];
    if ((t & 63) == 0) ws[t >> 6] = v;
    __syncthreads();
    if (t == 0) bsum[blockIdx.x] = ws[0] + ws[1] + ws[2] + ws[3];
}

__global__ __launch_bounds__(256) void scan2_kernel(const int* __restrict__ deg,
                                                    const int* __restrict__ bsum,
                                                    int* __restrict__ offs, int n) {
    const int b = blockIdx.x, t = threadIdx.x;
    const int lane = t & 63, w = t >> 6;

    int contrib = (t < b) ? bsum[t] : 0;
#pragma unroll
    for (int o = 1; o < 64; o <<= 1) contrib += __shfl_xor(contrib, o, 64);
    __shared__ int wsum[4];
    if (lane == 0) wsum[w] = contrib;
    __syncthreads();
    const int base = wsum[0] + wsum[1] + wsum[2] + wsum[3];

    const int i = b * 256 + t;
    const int v = (i < n) ? deg[i] : 0;
    int incl = v;
#pragma unroll
    for (int o = 1; o < 64; o <<= 1) {
        const int u = __shfl_up(incl, o, 64);
        if (lane >= o) incl += u;
    }
    __shared__ int wtot[4];
    if (lane == 63) wtot[w] = incl;
    __syncthreads();
    int wbase = 0;
#pragma unroll
    for (int k = 0; k < 4; ++k)
        if (k < w) wbase += wtot[k];

    const int excl = base + wbase + incl - v;
    if (i < n) offs[i] = excl;
    if (i == n - 1) offs[n] = excl + v;
}

// Pure gather + scatter: no atomics (rank precomputed in deg_kernel).
__global__ void fill_kernel(const int* __restrict__ src, const int* __restrict__ dst,
                            const int* __restrict__ offs, const int* __restrict__ rank,
                            int* __restrict__ csr_src, int E) {
    int i = blockIdx.x * blockDim.x + threadIdx.x;
    if (i < E) {
        csr_src[offs[dst[i]] + rank[i]] = src[i];
    }
}

// ---------------- conversion kernels ----------------

// X f32 -> bf16, 8 elems/thread (32B load, 16B store).
__global__ void cvt_x_kernel(const float4* __restrict__ X4, bf16x8* __restrict__ O8,
                             int n8) {
    int i = blockIdx.x * blockDim.x + threadIdx.x;
    if (i < n8) {
        const float4 a = X4[i * 2];
        const float4 b = X4[i * 2 + 1];
        bf16x8 v;
        v[0] = (short)f2bf(a.x); v[1] = (short)f2bf(a.y);
        v[2] = (short)f2bf(a.z); v[3] = (short)f2bf(a.w);
        v[4] = (short)f2bf(b.x); v[5] = (short)f2bf(b.y);
        v[6] = (short)f2bf(b.z); v[7] = (short)f2bf(b.w);
        O8[i] = v;
    }
}

// Wt[c][k] = bf16(W[k][c]). W1: 256x256, W2: 256x64. One dispatch.
__global__ void cvt_w_kernel(const float* __restrict__ W1, const float* __restrict__ W2,
                             unsigned short* __restrict__ Wt1,
                             unsigned short* __restrict__ Wt2) {
    const int k = blockIdx.x, c = threadIdx.x;
    Wt1[c * 256 + k] = f2bf(W1[k * 256 + c]);
    if (c < 64) Wt2[c * 256 + k] = f2bf(W2[k * 64 + c]);
}

// ---------------- layer-1 GEMM: LDS-tiled bf16 MFMA ----------------
// Staging is a pure bf16 copy (R7 fused f32->bf16 staging was VALU-bound:
// ~100 conversion cycles vs 160 MFMA cycles per k-step).
__global__ __launch_bounds__(256) void gemm1_mfma(const unsigned short* __restrict__ Xbf,
                                                  const unsigned short* __restrict__ Wt,
                                                  const float* __restrict__ AL,
                                                  const float* __restrict__ AR,
                                                  unsigned short* __restrict__ Hout,
                                                  float* __restrict__ el,
                                                  float* __restrict__ er, int n) {
    constexpr int LDR = 72;
    __shared__ __align__(16) unsigned short Xs[128 * LDR];
    __shared__ __align__(16) unsigned short Ws[128 * LDR];

    const int tid = threadIdx.x;
    const int wave = tid >> 6, lane = tid & 63;
    const int col16 = lane & 15, quad = lane >> 4;
    const int node0 = blockIdx.x * 128;
    const int fb = blockIdx.y;

    f32x4 acc[8][2];
#pragma unroll
    for (int ft = 0; ft < 8; ++ft)
#pragma unroll
        for (int nt = 0; nt < 2; ++nt) acc[ft][nt] = (f32x4){0.f, 0.f, 0.f, 0.f};

    const int rr = tid >> 3;
    const int cc = (tid & 7) * 8;

    for (int k0 = 0; k0 < 256; k0 += 64) {
#pragma unroll
        for (int p = 0; p < 4; ++p) {
            const int row = rr + p * 32;
            int gx = node0 + row; if (gx >= n) gx = n - 1;
            *(bf16x8*)&Xs[row * LDR + cc] =
                *(const bf16x8*)&Xbf[(long long)gx * 256 + k0 + cc];
            *(bf16x8*)&Ws[row * LDR + cc] =
                *(const bf16x8*)&Wt[((long long)(fb * 128 + row)) * 256 + k0 + cc];
        }
        __syncthreads();
#pragma unroll
        for (int ks = 0; ks < 64; ks += 32) {
            bf16x8 bfrag[2];
#pragma unroll
            for (int nt = 0; nt < 2; ++nt)
                bfrag[nt] = *(const bf16x8*)&Xs[(wave * 32 + nt * 16 + col16) * LDR +
                                                ks + quad * 8];
#pragma unroll
            for (int ft = 0; ft < 8; ++ft) {
                const bf16x8 afrag =
                    *(const bf16x8*)&Ws[(ft * 16 + col16) * LDR + ks + quad * 8];
                acc[ft][0] = __builtin_amdgcn_mfma_f32_16x16x32_bf16(afrag, bfrag[0],
                                                                     acc[ft][0], 0, 0, 0);
                acc[ft][1] = __builtin_amdgcn_mfma_f32_16x16x32_bf16(afrag, bfrag[1],
                                                                     acc[ft][1], 0, 0, 0);
            }
        }
        __syncthreads();
    }

    float elp[2][2] = {{0.f, 0.f}, {0.f, 0.f}};
    float erp[2][2] = {{0.f, 0.f}, {0.f, 0.f}};
#pragma unroll
    for (int ft = 0; ft < 8; ++ft) {
        const int hb = ft >> 2;
        const int head = fb * 2 + hb;
        float alw[4], arw[4];
#pragma unroll
        for (int r = 0; r < 4; ++r) {
            const int d = (ft & 3) * 16 + quad * 4 + r;
            alw[r] = AL[head * 64 + d];
            arw[r] = AR[head * 64 + d];
        }
#pragma unroll
        for (int nt = 0; nt < 2; ++nt) {
            const int node = node0 + wave * 32 + nt * 16 + col16;
            if (node < n) {
                ushort4 pk;
                pk.x = f2bf(acc[ft][nt][0]); pk.y = f2bf(acc[ft][nt][1]);
                pk.z = f2bf(acc[ft][nt][2]); pk.w = f2bf(acc[ft][nt][3]);
                *(ushort4*)&Hout[(long long)node * 256 + fb * 128 + ft * 16 + quad * 4] = pk;
            }
#pragma unroll
            for (int r = 0; r < 4; ++r) {
                elp[nt][hb] = fmaf(acc[ft][nt][r], alw[r], elp[nt][hb]);
                erp[nt][hb] = fmaf(acc[ft][nt][r], arw[r], erp[nt][hb]);
            }
        }
    }
#pragma unroll
    for (int nt = 0; nt < 2; ++nt)
#pragma unroll
        for (int hb = 0; hb < 2; ++hb) {
            elp[nt][hb] += __shfl_xor(elp[nt][hb], 16, 64);
            elp[nt][hb] += __shfl_xor(elp[nt][hb], 32, 64);
            erp[nt][hb] += __shfl_xor(erp[nt][hb], 16, 64);
            erp[nt][hb] += __shfl_xor(erp[nt][hb], 32, 64);
        }
    if (quad == 0) {
#pragma unroll
        for (int nt = 0; nt < 2; ++nt) {
            const int node = node0 + wave * 32 + nt * 16 + col16;
            if (node < n) {
#pragma unroll
                for (int hb = 0; hb < 2; ++hb) {
                    el[node * 4 + fb * 2 + hb] = elp[nt][hb];
                    er[node * 4 + fb * 2 + hb] = erp[nt][hb];
                }
            }
        }
    }
}

// ---------------- layer-2 GEMM: LDS-tiled bf16 MFMA (M=64) ----------------
// Output h2 stored as fp16 (halves aggr2's gather bytes; 2^-11 rel err).
__global__ __launch_bounds__(256) void gemm2_mfma(const unsigned short* __restrict__ Xbf,
                                                  const unsigned short* __restrict__ Wt,
                                                  const float* __restrict__ AL,
                                                  const float* __restrict__ AR,
                                                  unsigned short* __restrict__ Hout,
                                                  float* __restrict__ el,
                                                  float* __restrict__ er, int n) {
    constexpr int LDR = 72;
    __shared__ __align__(16) unsigned short Xs[128 * LDR];
    __shared__ __align__(16) unsigned short Ws[64 * LDR];

    const int tid = threadIdx.x;
    const int wave = tid >> 6, lane = tid & 63;
    const int col16 = lane & 15, quad = lane >> 4;
    const int node0 = blockIdx.x * 128;

    f32x4 acc[4][2];
#pragma unroll
    for (int ft = 0; ft < 4; ++ft)
#pragma unroll
        for (int nt = 0; nt < 2; ++nt) acc[ft][nt] = (f32x4){0.f, 0.f, 0.f, 0.f};

    const int rr = tid >> 3;
    const int cc = (tid & 7) * 8;

    for (int k0 = 0; k0 < 256; k0 += 64) {
#pragma unroll
        for (int p = 0; p < 4; ++p) {
            const int row = rr + p * 32;
            int gx = node0 + row; if (gx >= n) gx = n - 1;
            *(bf16x8*)&Xs[row * LDR + cc] =
                *(const bf16x8*)&Xbf[(long long)gx * 256 + k0 + cc];
        }
#pragma unroll
        for (int p = 0; p < 2; ++p) {
            const int row = rr + p * 32;
            *(bf16x8*)&Ws[row * LDR + cc] =
                *(const bf16x8*)&Wt[(long long)row * 256 + k0 + cc];
        }
        __syncthreads();
#pragma unroll
        for (int ks = 0; ks < 64; ks += 32) {
            bf16x8 bfrag[2];
#pragma unroll
            for (int nt = 0; nt < 2; ++nt)
                bfrag[nt] = *(const bf16x8*)&Xs[(wave * 32 + nt * 16 + col16) * LDR +
                                                ks + quad * 8];
#pragma unroll
            for (int ft = 0; ft < 4; ++ft) {
                const bf16x8 afrag =
                    *(const bf16x8*)&Ws[(ft * 16 + col16) * LDR + ks + quad * 8];
                acc[ft][0] = __builtin_amdgcn_mfma_f32_16x16x32_bf16(afrag, bfrag[0],
                                                                     acc[ft][0], 0, 0, 0);
                acc[ft][1] = __builtin_amdgcn_mfma_f32_16x16x32_bf16(afrag, bfrag[1],
                                                                     acc[ft][1], 0, 0, 0);
            }
        }
        __syncthreads();
    }

    float elp[2] = {0.f, 0.f}, erp[2] = {0.f, 0.f};
#pragma unroll
    for (int ft = 0; ft < 4; ++ft) {
        float alw[4], arw[4];
#pragma unroll
        for (int r = 0; r < 4; ++r) {
            const int d = ft * 16 + quad * 4 + r;
            alw[r] = AL[d];
            arw[r] = AR[d];
        }
#pragma unroll
        for (int nt = 0; nt < 2; ++nt) {
            const int node = node0 + wave * 32 + nt * 16 + col16;
            if (node < n) {
                ushort4 pk;
                pk.x = __half_as_ushort(__float2half(acc[ft][nt][0]));
                pk.y = __half_as_ushort(__float2half(acc[ft][nt][1]));
                pk.z = __half_as_ushort(__float2half(acc[ft][nt][2]));
                pk.w = __half_as_ushort(__float2half(acc[ft][nt][3]));
                *(ushort4*)&Hout[(long long)node * 64 + ft * 16 + quad * 4] = pk;
            }
#pragma unroll
            for (int r = 0; r < 4; ++r) {
                elp[nt] = fmaf(acc[ft][nt][r], alw[r], elp[nt]);
                erp[nt] = fmaf(acc[ft][nt][r], arw[r], erp[nt]);
            }
        }
    }
#pragma unroll
    for (int nt = 0; nt < 2; ++nt) {
        elp[nt] += __shfl_xor(elp[nt], 16, 64);
        elp[nt] += __shfl_xor(elp[nt], 32, 64);
        erp[nt] += __shfl_xor(erp[nt], 16, 64);
        erp[nt] += __shfl_xor(erp[nt], 32, 64);
    }
    if (quad == 0) {
#pragma unroll
        for (int nt = 0; nt < 2; ++nt) {
            const int node = node0 + wave * 32 + nt * 16 + col16;
            if (node < n) {
                el[node] = elp[nt];
                er[node] = erp[nt];
            }
        }
    }
}

// ---------------- aggregation, 4 edges per wave-iteration ----------------
// Softmax numerators inline. One-iteration s-prefetch pipeline hides the
// csr->s->gather dependent chain. unroll 2 only (R4: unroll 4 kills occupancy).
__global__ __launch_bounds__(256) void aggr1_kernel(const unsigned short* __restrict__ Hf,
                                                    const float* __restrict__ el,
                                                    const float* __restrict__ er,
                                                    const int* __restrict__ offs,
                                                    const int* __restrict__ csr,
                                                    const float* __restrict__ bias,
                                                    unsigned short* __restrict__ out,
                                                    int n) {
    const int node = (blockIdx.x * blockDim.x + threadIdx.x) >> 6;
    if (node >= n) return;
    const int lane = threadIdx.x & 63;
    const int g = lane >> 4;       // edge subgroup
    const int r = lane & 15;       // feature slot: feats r*16 .. r*16+15
    const int h = r >> 2;          // head of this feature slot
    const int beg = offs[node], end = offs[node + 1];
    const float erv = er[node * 4 + h];

    float acc[16];
#pragma unroll
    for (int q = 0; q < 16; ++q) acc[q] = 0.f;
    float l = 0.f;

    const int nb = (end - beg + 3) >> 2;
    int ci = beg + g; if (ci >= end) ci = end - 1;
    int s = csr[ci];                       // prologue: first edge index
#pragma unroll 2
    for (int it = 0; it < nb; ++it) {
        const int ei = beg + it * 4 + g;
        const bool ok = ei < end;
        int nci = ei + 4; if (nci >= end) nci = end - 1;
        const int sn = csr[nci];           // prefetch next iteration's source
        float e = el[s * 4 + h] + erv;
        e = (e > 0.f) ? e : SLOPE * e;
        float p = __expf(fminf(e, 80.f));
        if (!ok) p = 0.f;
        const uint4* hp = (const uint4*)(Hf + (s << 8) + (r << 4));
        const uint4 u0 = hp[0];
        const uint4 u1 = hp[1];
        l += p;
        const unsigned uu[8] = {u0.x, u0.y, u0.z, u0.w, u1.x, u1.y, u1.z, u1.w};
#pragma unroll
        for (int q = 0; q < 8; ++q) {
            const float flo = __uint_as_float(uu[q] << 16);
            const float fhi = __uint_as_float(uu[q] & 0xFFFF0000u);
            acc[2 * q]     = fmaf(p, flo, acc[2 * q]);
            acc[2 * q + 1] = fmaf(p, fhi, acc[2 * q + 1]);
        }
        s = sn;
    }

#pragma unroll
    for (int q = 0; q < 16; ++q) {
        acc[q] += __shfl_xor(acc[q], 16, 64);
        acc[q] += __shfl_xor(acc[q], 32, 64);
    }
    l += __shfl_xor(l, 16, 64);
    l += __shfl_xor(l, 32, 64);

    if (g == 0) {
        const float inv = (l > 0.f) ? 1.f / l : 0.f;
        unsigned o[8];
#pragma unroll
        for (int q = 0; q < 8; ++q) {
            float v0 = acc[2 * q]     * inv + bias[r * 16 + 2 * q];
            float v1 = acc[2 * q + 1] * inv + bias[r * 16 + 2 * q + 1];
            v0 = (v0 > 0.f) ? v0 : expm1f(v0);   // ELU
            v1 = (v1 > 0.f) ? v1 : expm1f(v1);
            o[q] = (unsigned)f2bf(v0) | ((unsigned)f2bf(v1) << 16);
        }
        uint4* op = (uint4*)(out + (node << 8) + (r << 4));
        op[0] = make_uint4(o[0], o[1], o[2], o[3]);
        op[1] = make_uint4(o[4], o[5], o[6], o[7]);
    }
}

// Layer 2: H=1, D=64 fp16. 16 lanes per edge (lane covers 4 feats, 1 uint2).
__global__ __launch_bounds__(256) void aggr2_kernel(const unsigned short* __restrict__ Hf,
                                                    const float* __restrict__ el,
                                                    const float* __restrict__ er,
                                                    const int* __restrict__ offs,
                                                    const int* __restrict__ csr,
                                                    const float* __restrict__ bias,
                                                    float* __restrict__ out, int n) {
    const int node = (blockIdx.x * blockDim.x + threadIdx.x) >> 6;
    if (node >= n) return;
    const int lane = threadIdx.x & 63;
    const int g = lane >> 4;
    const int r = lane & 15;
    const int beg = offs[node], end = offs[node + 1];
    const float erv = er[node];

    float a0 = 0.f, a1 = 0.f, a2 = 0.f, a3 = 0.f, l = 0.f;
    const int nb = (end - beg + 3) >> 2;
    int ci = beg + g; if (ci >= end) ci = end - 1;
    int s = csr[ci];
#pragma unroll 2
    for (int it = 0; it < nb; ++it) {
        const int ei = beg + it * 4 + g;
        const bool ok = ei < end;
        int nci = ei + 4; if (nci >= end) nci = end - 1;
        const int sn = csr[nci];
        float e = el[s] + erv;
        e = (e > 0.f) ? e : SLOPE * e;
        float p = __expf(fminf(e, 80.f));
        if (!ok) p = 0.f;
        const uint2 u = *(const uint2*)(Hf + (s << 6) + (r << 2));   // 8B fp16 x4
        const float h0 = __half2float(__ushort_as_half((unsigned short)(u.x & 0xFFFFu)));
        const float h1 = __half2float(__ushort_as_half((unsigned short)(u.x >> 16)));
        const float h2 = __half2float(__ushort_as_half((unsigned short)(u.y & 0xFFFFu)));
        const float h3 = __half2float(__ushort_as_half((unsigned short)(u.y >> 16)));
        l += p;
        a0 = fmaf(p, h0, a0);
        a1 = fmaf(p, h1, a1);
        a2 = fmaf(p, h2, a2);
        a3 = fmaf(p, h3, a3);
        s = sn;
    }

    a0 += __shfl_xor(a0, 16, 64); a0 += __shfl_xor(a0, 32, 64);
    a1 += __shfl_xor(a1, 16, 64); a1 += __shfl_xor(a1, 32, 64);
    a2 += __shfl_xor(a2, 16, 64); a2 += __shfl_xor(a2, 32, 64);
    a3 += __shfl_xor(a3, 16, 64); a3 += __shfl_xor(a3, 32, 64);
    l  += __shfl_xor(l, 16, 64);  l  += __shfl_xor(l, 32, 64);

    if (g == 0) {
        const float inv = (l > 0.f) ? 1.f / l : 0.f;
        const float4 b4 = *(const float4*)(bias + r * 4);
        *(float4*)(out + (node << 6) + (r << 2)) =
            make_float4(fmaf(a0, inv, b4.x), fmaf(a1, inv, b4.y),
                        fmaf(a2, inv, b4.z), fmaf(a3, inv, b4.w));
    }
}

// ---------------- launch ----------------

extern "C" void kernel_launch(void* const* d_in, const int* in_sizes, int n_in,
                              void* d_out, int out_size, void* d_ws, size_t ws_size,
                              hipStream_t stream) {
    const float* feat = (const float*)d_in[0];
    const int*   src  = (const int*)d_in[1];
    const int*   dst  = (const int*)d_in[2];
    const float* W1   = (const float*)d_in[3];
    const float* al1  = (const float*)d_in[4];
    const float* ar1  = (const float*)d_in[5];
    const float* b1   = (const float*)d_in[6];
    const float* W2   = (const float*)d_in[7];
    const float* al2  = (const float*)d_in[8];
    const float* ar2  = (const float*)d_in[9];
    const float* b2   = (const float*)d_in[10];
    float* out = (float*)d_out;

    const int IN = 256, HID = 64, OUT = 64, H1 = 4, H2 = 1;
    const int N = in_sizes[0] / IN;   // 50000
    const int E = in_sizes[1];        // 800000

    size_t off = 0;
    auto alloc = [&](size_t bytes) {
        void* p = (char*)d_ws + off;
        off += (bytes + 255) & ~(size_t)255;
        return p;
    };
    int*   deg    = (int*)alloc((size_t)N * 4);
    int*   offs   = (int*)alloc((size_t)(N + 1) * 4);
    int*   bsum   = (int*)alloc((size_t)256 * 4);
    int*   rank   = (int*)alloc((size_t)E * 4);
    int*   csr    = (int*)alloc((size_t)E * 4);
    unsigned short* h1   = (unsigned short*)alloc((size_t)N * H1 * HID * 2); // bf16
    unsigned short* xbf  = (unsigned short*)alloc((size_t)N * IN * 2);       // bf16 X
    unsigned short* wt1  = (unsigned short*)alloc((size_t)IN * H1 * HID * 2);// bf16 W1^T
    unsigned short* wt2  = (unsigned short*)alloc((size_t)H1 * HID * H2 * OUT * 2); // W2^T
    unsigned short* x2bf = (unsigned short*)alloc((size_t)N * H1 * HID * 2); // bf16 x2
    unsigned short* h2   = (unsigned short*)alloc((size_t)N * H2 * OUT * 2); // fp16
    float* el1    = (float*)alloc((size_t)N * H1 * 4);
    float* er1    = (float*)alloc((size_t)N * H1 * 4);
    float* el2    = (float*)alloc((size_t)N * H2 * 4);
    float* er2    = (float*)alloc((size_t)N * H2 * 4);
    (void)ws_size;

    hipMemsetAsync(deg, 0, (size_t)N * 4, stream);

    const int nb = (N + 255) / 256;   // 196 <= 256 (required by scan2_kernel)
    deg_kernel<<<(E + 255) / 256, 256, 0, stream>>>(dst, deg, rank, E);
    psum_kernel<<<nb, 256, 0, stream>>>(deg, bsum, N);
    scan2_kernel<<<nb, 256, 0, stream>>>(deg, bsum, offs, N);
    fill_kernel<<<(E + 255) / 256, 256, 0, stream>>>(src, dst, offs, rank, csr, E);

    // conversions
    {
        const int n8 = N * IN / 8;
        cvt_x_kernel<<<(n8 + 255) / 256, 256, 0, stream>>>((const float4*)feat,
                                                           (bf16x8*)xbf, n8);
        cvt_w_kernel<<<256, 256, 0, stream>>>(W1, W2, wt1, wt2);
    }

    // ---- layer 1 ----
    {
        dim3 g((N + 127) / 128, 2);
        gemm1_mfma<<<g, 256, 0, stream>>>(xbf, wt1, al1, ar1, h1, el1, er1, N);
    }
    aggr1_kernel<<<(N + 3) / 4, 256, 0, stream>>>(h1, el1, er1, offs, csr, b1, x2bf, N);
    // ---- layer 2 ----
    gemm2_mfma<<<(N + 127) / 128, 256, 0, stream>>>(x2bf, wt2, al2, ar2, h2, el2, er2, N);
    aggr2_kernel<<<(N + 3) / 4, 256, 0, stream>>>(h2, el2, er2, offs, csr, b2, out, N);
}

// Round 9
// 299.335 us; speedup vs baseline: 1.0212x; 1.0212x over previous
//
#include <hip/hip_runtime.h>
#include <hip/hip_bf16.h>
#include <hip/hip_fp16.h>
#include <math.h>

#define SLOPE 0.2f

typedef __attribute__((ext_vector_type(8))) short bf16x8;
typedef __attribute__((ext_vector_type(4))) float f32x4;

// bf16 helpers (manual, RNE)
__device__ inline unsigned short f2bf(float f) {
    unsigned u = __float_as_uint(f);
    u += 0x7FFF + ((u >> 16) & 1);
    return (unsigned short)(u >> 16);
}
__device__ inline float bf2f(unsigned short s) {
    return __uint_as_float(((unsigned)s) << 16);
}
// HW packed f32x2 -> bf16x2 (RNE), gfx950. lo = bf16(a), hi = bf16(b).
__device__ inline unsigned cvt_pk_bf16(float a, float b) {
    unsigned r;
    asm("v_cvt_pk_bf16_f32 %0, %1, %2" : "=v"(r) : "v"(a), "v"(b));
    return r;
}

// ---------------- CSR build (separate dispatches; R6: coop grid.sync ~100us
// per barrier on MI355X -> NEVER use cooperative launch for this) ----------

// rank[i] = arrival order of edge i at its dst node (doubles as cursor pass).
__global__ void deg_kernel(const int* __restrict__ dst, int* __restrict__ deg,
                           int* __restrict__ rank, int E) {
    int i = blockIdx.x * blockDim.x + threadIdx.x;
    if (i < E) rank[i] = atomicAdd(&deg[dst[i]], 1);
}

// Two-level device-wide exclusive scan (N <= 65536 so nb <= 256).
__global__ __launch_bounds__(256) void psum_kernel(const int* __restrict__ deg,
                                                   int* __restrict__ bsum, int n) {
    const int t = threadIdx.x;
    const int i = blockIdx.x * 256 + t;
    int v = (i < n) ? deg[i] : 0;
#pragma unroll
    for (int o = 1; o < 64; o <<= 1) v += __shfl_xor(v, o, 64);
    __shared__ int ws[4];
    if ((t & 63) == 0) ws[t >> 6] = v;
    __syncthreads();
    if (t == 0) bsum[blockIdx.x] = ws[0] + ws[1] + ws[2] + ws[3];
}

__global__ __launch_bounds__(256) void scan2_kernel(const int* __restrict__ deg,
                                                    const int* __restrict__ bsum,
                                                    int* __restrict__ offs, int n) {
    const int b = blockIdx.x, t = threadIdx.x;
    const int lane = t & 63, w = t >> 6;

    int contrib = (t < b) ? bsum[t] : 0;
#pragma unroll
    for (int o = 1; o < 64; o <<= 1) contrib += __shfl_xor(contrib, o, 64);
    __shared__ int wsum[4];
    if (lane == 0) wsum[w] = contrib;
    __syncthreads();
    const int base = wsum[0] + wsum[1] + wsum[2] + wsum[3];

    const int i = b * 256 + t;
    const int v = (i < n) ? deg[i] : 0;
    int incl = v;
#pragma unroll
    for (int o = 1; o < 64; o <<= 1) {
        const int u = __shfl_up(incl, o, 64);
        if (lane >= o) incl += u;
    }
    __shared__ int wtot[4];
    if (lane == 63) wtot[w] = incl;
    __syncthreads();
    int wbase = 0;
#pragma unroll
    for (int k = 0; k < 4; ++k)
        if (k < w) wbase += wtot[k];

    const int excl = base + wbase + incl - v;
    if (i < n) offs[i] = excl;
    if (i == n - 1) offs[n] = excl + v;
}

// Pure gather + scatter: no atomics (rank precomputed in deg_kernel).
__global__ void fill_kernel(const int* __restrict__ src, const int* __restrict__ dst,
                            const int* __restrict__ offs, const int* __restrict__ rank,
                            int* __restrict__ csr_src, int E) {
    int i = blockIdx.x * blockDim.x + threadIdx.x;
    if (i < E) {
        csr_src[offs[dst[i]] + rank[i]] = src[i];
    }
}

// ---------------- weight conversion (both layers, 1 dispatch) ----------------
// Wt[c][k] = bf16(W[k][c]). W1: 256x256, W2: 256x64.
__global__ void cvt_w_kernel(const float* __restrict__ W1, const float* __restrict__ W2,
                             unsigned short* __restrict__ Wt1,
                             unsigned short* __restrict__ Wt2) {
    const int k = blockIdx.x, c = threadIdx.x;
    Wt1[c * 256 + k] = f2bf(W1[k * 256 + c]);
    if (c < 64) Wt2[c * 256 + k] = f2bf(W2[k * 64 + c]);
}

// ---------------- layer-1 GEMM: LDS-tiled bf16 MFMA ----------------
// X read as f32, converted during staging via v_cvt_pk_bf16_f32 (4 insts per
// 8 elems vs ~32 for manual RNE arithmetic -> staging no longer VALU-bound).
__global__ __launch_bounds__(256) void gemm1_mfma(const float* __restrict__ Xf,
                                                  const unsigned short* __restrict__ Wt,
                                                  const float* __restrict__ AL,
                                                  const float* __restrict__ AR,
                                                  unsigned short* __restrict__ Hout,
                                                  float* __restrict__ el,
                                                  float* __restrict__ er, int n) {
    constexpr int LDR = 72;
    __shared__ __align__(16) unsigned short Xs[128 * LDR];
    __shared__ __align__(16) unsigned short Ws[128 * LDR];

    const int tid = threadIdx.x;
    const int wave = tid >> 6, lane = tid & 63;
    const int col16 = lane & 15, quad = lane >> 4;
    const int node0 = blockIdx.x * 128;
    const int fb = blockIdx.y;

    f32x4 acc[8][2];
#pragma unroll
    for (int ft = 0; ft < 8; ++ft)
#pragma unroll
        for (int nt = 0; nt < 2; ++nt) acc[ft][nt] = (f32x4){0.f, 0.f, 0.f, 0.f};

    const int rr = tid >> 3;
    const int cc = (tid & 7) * 8;

    for (int k0 = 0; k0 < 256; k0 += 64) {
#pragma unroll
        for (int p = 0; p < 4; ++p) {
            const int row = rr + p * 32;
            int gx = node0 + row; if (gx >= n) gx = n - 1;
            const float4* xp = (const float4*)&Xf[(long long)gx * 256 + k0 + cc];
            const float4 a = xp[0];
            const float4 b = xp[1];
            uint4 pk;
            pk.x = cvt_pk_bf16(a.x, a.y);
            pk.y = cvt_pk_bf16(a.z, a.w);
            pk.z = cvt_pk_bf16(b.x, b.y);
            pk.w = cvt_pk_bf16(b.z, b.w);
            *(uint4*)&Xs[row * LDR + cc] = pk;
            *(bf16x8*)&Ws[row * LDR + cc] =
                *(const bf16x8*)&Wt[((long long)(fb * 128 + row)) * 256 + k0 + cc];
        }
        __syncthreads();
#pragma unroll
        for (int ks = 0; ks < 64; ks += 32) {
            bf16x8 bfrag[2];
#pragma unroll
            for (int nt = 0; nt < 2; ++nt)
                bfrag[nt] = *(const bf16x8*)&Xs[(wave * 32 + nt * 16 + col16) * LDR +
                                                ks + quad * 8];
#pragma unroll
            for (int ft = 0; ft < 8; ++ft) {
                const bf16x8 afrag =
                    *(const bf16x8*)&Ws[(ft * 16 + col16) * LDR + ks + quad * 8];
                acc[ft][0] = __builtin_amdgcn_mfma_f32_16x16x32_bf16(afrag, bfrag[0],
                                                                     acc[ft][0], 0, 0, 0);
                acc[ft][1] = __builtin_amdgcn_mfma_f32_16x16x32_bf16(afrag, bfrag[1],
                                                                     acc[ft][1], 0, 0, 0);
            }
        }
        __syncthreads();
    }

    float elp[2][2] = {{0.f, 0.f}, {0.f, 0.f}};
    float erp[2][2] = {{0.f, 0.f}, {0.f, 0.f}};
#pragma unroll
    for (int ft = 0; ft < 8; ++ft) {
        const int hb = ft >> 2;
        const int head = fb * 2 + hb;
        float alw[4], arw[4];
#pragma unroll
        for (int r = 0; r < 4; ++r) {
            const int d = (ft & 3) * 16 + quad * 4 + r;
            alw[r] = AL[head * 64 + d];
            arw[r] = AR[head * 64 + d];
        }
#pragma unroll
        for (int nt = 0; nt < 2; ++nt) {
            const int node = node0 + wave * 32 + nt * 16 + col16;
            if (node < n) {
                uint2 pk;
                pk.x = cvt_pk_bf16(acc[ft][nt][0], acc[ft][nt][1]);
                pk.y = cvt_pk_bf16(acc[ft][nt][2], acc[ft][nt][3]);
                *(uint2*)&Hout[(long long)node * 256 + fb * 128 + ft * 16 + quad * 4] = pk;
            }
#pragma unroll
            for (int r = 0; r < 4; ++r) {
                elp[nt][hb] = fmaf(acc[ft][nt][r], alw[r], elp[nt][hb]);
                erp[nt][hb] = fmaf(acc[ft][nt][r], arw[r], erp[nt][hb]);
            }
        }
    }
#pragma unroll
    for (int nt = 0; nt < 2; ++nt)
#pragma unroll
        for (int hb = 0; hb < 2; ++hb) {
            elp[nt][hb] += __shfl_xor(elp[nt][hb], 16, 64);
            elp[nt][hb] += __shfl_xor(elp[nt][hb], 32, 64);
            erp[nt][hb] += __shfl_xor(erp[nt][hb], 16, 64);
            erp[nt][hb] += __shfl_xor(erp[nt][hb], 32, 64);
        }
    if (quad == 0) {
#pragma unroll
        for (int nt = 0; nt < 2; ++nt) {
            const int node = node0 + wave * 32 + nt * 16 + col16;
            if (node < n) {
#pragma unroll
                for (int hb = 0; hb < 2; ++hb) {
                    el[node * 4 + fb * 2 + hb] = elp[nt][hb];
                    er[node * 4 + fb * 2 + hb] = erp[nt][hb];
                }
            }
        }
    }
}

// ---------------- layer-2 GEMM: LDS-tiled bf16 MFMA (M=64) ----------------
// Output h2 stored as fp16 (halves aggr2's gather bytes; 2^-11 rel err).
__global__ __launch_bounds__(256) void gemm2_mfma(const unsigned short* __restrict__ Xbf,
                                                  const unsigned short* __restrict__ Wt,
                                                  const float* __restrict__ AL,
                                                  const float* __restrict__ AR,
                                                  unsigned short* __restrict__ Hout,
                                                  float* __restrict__ el,
                                                  float* __restrict__ er, int n) {
    constexpr int LDR = 72;
    __shared__ __align__(16) unsigned short Xs[128 * LDR];
    __shared__ __align__(16) unsigned short Ws[64 * LDR];

    const int tid = threadIdx.x;
    const int wave = tid >> 6, lane = tid & 63;
    const int col16 = lane & 15, quad = lane >> 4;
    const int node0 = blockIdx.x * 128;

    f32x4 acc[4][2];
#pragma unroll
    for (int ft = 0; ft < 4; ++ft)
#pragma unroll
        for (int nt = 0; nt < 2; ++nt) acc[ft][nt] = (f32x4){0.f, 0.f, 0.f, 0.f};

    const int rr = tid >> 3;
    const int cc = (tid & 7) * 8;

    for (int k0 = 0; k0 < 256; k0 += 64) {
#pragma unroll
        for (int p = 0; p < 4; ++p) {
            const int row = rr + p * 32;
            int gx = node0 + row; if (gx >= n) gx = n - 1;
            *(bf16x8*)&Xs[row * LDR + cc] =
                *(const bf16x8*)&Xbf[(long long)gx * 256 + k0 + cc];
        }
#pragma unroll
        for (int p = 0; p < 2; ++p) {
            const int row = rr + p * 32;
            *(bf16x8*)&Ws[row * LDR + cc] =
                *(const bf16x8*)&Wt[(long long)row * 256 + k0 + cc];
        }
        __syncthreads();
#pragma unroll
        for (int ks = 0; ks < 64; ks += 32) {
            bf16x8 bfrag[2];
#pragma unroll
            for (int nt = 0; nt < 2; ++nt)
                bfrag[nt] = *(const bf16x8*)&Xs[(wave * 32 + nt * 16 + col16) * LDR +
                                                ks + quad * 8];
#pragma unroll
            for (int ft = 0; ft < 4; ++ft) {
                const bf16x8 afrag =
                    *(const bf16x8*)&Ws[(ft * 16 + col16) * LDR + ks + quad * 8];
                acc[ft][0] = __builtin_amdgcn_mfma_f32_16x16x32_bf16(afrag, bfrag[0],
                                                                     acc[ft][0], 0, 0, 0);
                acc[ft][1] = __builtin_amdgcn_mfma_f32_16x16x32_bf16(afrag, bfrag[1],
                                                                     acc[ft][1], 0, 0, 0);
            }
        }
        __syncthreads();
    }

    float elp[2] = {0.f, 0.f}, erp[2] = {0.f, 0.f};
#pragma unroll
    for (int ft = 0; ft < 4; ++ft) {
        float alw[4], arw[4];
#pragma unroll
        for (int r = 0; r < 4; ++r) {
            const int d = ft * 16 + quad * 4 + r;
            alw[r] = AL[d];
            arw[r] = AR[d];
        }
#pragma unroll
        for (int nt = 0; nt < 2; ++nt) {
            const int node = node0 + wave * 32 + nt * 16 + col16;
            if (node < n) {
                ushort4 pk;
                pk.x = __half_as_ushort(__float2half(acc[ft][nt][0]));
                pk.y = __half_as_ushort(__float2half(acc[ft][nt][1]));
                pk.z = __half_as_ushort(__float2half(acc[ft][nt][2]));
                pk.w = __half_as_ushort(__float2half(acc[ft][nt][3]));
                *(ushort4*)&Hout[(long long)node * 64 + ft * 16 + quad * 4] = pk;
            }
#pragma unroll
            for (int r = 0; r < 4; ++r) {
                elp[nt] = fmaf(acc[ft][nt][r], alw[r], elp[nt]);
                erp[nt] = fmaf(acc[ft][nt][r], arw[r], erp[nt]);
            }
        }
    }
#pragma unroll
    for (int nt = 0; nt < 2; ++nt) {
        elp[nt] += __shfl_xor(elp[nt], 16, 64);
        elp[nt] += __shfl_xor(elp[nt], 32, 64);
        erp[nt] += __shfl_xor(erp[nt], 16, 64);
        erp[nt] += __shfl_xor(erp[nt], 32, 64);
    }
    if (quad == 0) {
#pragma unroll
        for (int nt = 0; nt < 2; ++nt) {
            const int node = node0 + wave * 32 + nt * 16 + col16;
            if (node < n) {
                el[node] = elp[nt];
                er[node] = erp[nt];
            }
        }
    }
}

// ---------------- aggregation, 4 edges per wave-iteration ----------------
// Softmax numerators inline. One-iteration s-prefetch pipeline hides the
// csr->s->gather dependent chain. unroll 2 only (R4: unroll 4 kills occupancy).
__global__ __launch_bounds__(256) void aggr1_kernel(const unsigned short* __restrict__ Hf,
                                                    const float* __restrict__ el,
                                                    const float* __restrict__ er,
                                                    const int* __restrict__ offs,
                                                    const int* __restrict__ csr,
                                                    const float* __restrict__ bias,
                                                    unsigned short* __restrict__ out,
                                                    int n) {
    const int node = (blockIdx.x * blockDim.x + threadIdx.x) >> 6;
    if (node >= n) return;
    const int lane = threadIdx.x & 63;
    const int g = lane >> 4;       // edge subgroup
    const int r = lane & 15;       // feature slot: feats r*16 .. r*16+15
    const int h = r >> 2;          // head of this feature slot
    const int beg = offs[node], end = offs[node + 1];
    const float erv = er[node * 4 + h];

    float acc[16];
#pragma unroll
    for (int q = 0; q < 16; ++q) acc[q] = 0.f;
    float l = 0.f;

    const int nb = (end - beg + 3) >> 2;
    int ci = beg + g; if (ci >= end) ci = end - 1;
    int s = csr[ci];                       // prologue: first edge index
#pragma unroll 2
    for (int it = 0; it < nb; ++it) {
        const int ei = beg + it * 4 + g;
        const bool ok = ei < end;
        int nci = ei + 4; if (nci >= end) nci = end - 1;
        const int sn = csr[nci];           // prefetch next iteration's source
        float e = el[s * 4 + h] + erv;
        e = (e > 0.f) ? e : SLOPE * e;
        float p = __expf(fminf(e, 80.f));
        if (!ok) p = 0.f;
        const uint4* hp = (const uint4*)(Hf + (s << 8) + (r << 4));
        const uint4 u0 = hp[0];
        const uint4 u1 = hp[1];
        l += p;
        const unsigned uu[8] = {u0.x, u0.y, u0.z, u0.w, u1.x, u1.y, u1.z, u1.w};
#pragma unroll
        for (int q = 0; q < 8; ++q) {
            const float flo = __uint_as_float(uu[q] << 16);
            const float fhi = __uint_as_float(uu[q] & 0xFFFF0000u);
            acc[2 * q]     = fmaf(p, flo, acc[2 * q]);
            acc[2 * q + 1] = fmaf(p, fhi, acc[2 * q + 1]);
        }
        s = sn;
    }

#pragma unroll
    for (int q = 0; q < 16; ++q) {
        acc[q] += __shfl_xor(acc[q], 16, 64);
        acc[q] += __shfl_xor(acc[q], 32, 64);
    }
    l += __shfl_xor(l, 16, 64);
    l += __shfl_xor(l, 32, 64);

    if (g == 0) {
        const float inv = (l > 0.f) ? 1.f / l : 0.f;
        unsigned o[8];
#pragma unroll
        for (int q = 0; q < 8; ++q) {
            float v0 = acc[2 * q]     * inv + bias[r * 16 + 2 * q];
            float v1 = acc[2 * q + 1] * inv + bias[r * 16 + 2 * q + 1];
            v0 = (v0 > 0.f) ? v0 : expm1f(v0);   // ELU
            v1 = (v1 > 0.f) ? v1 : expm1f(v1);
            o[q] = cvt_pk_bf16(v0, v1);
        }
        uint4* op = (uint4*)(out + (node << 8) + (r << 4));
        op[0] = make_uint4(o[0], o[1], o[2], o[3]);
        op[1] = make_uint4(o[4], o[5], o[6], o[7]);
    }
}

// Layer 2: H=1, D=64 fp16. 16 lanes per edge (lane covers 4 feats, 1 uint2).
__global__ __launch_bounds__(256) void aggr2_kernel(const unsigned short* __restrict__ Hf,
                                                    const float* __restrict__ el,
                                                    const float* __restrict__ er,
                                                    const int* __restrict__ offs,
                                                    const int* __restrict__ csr,
                                                    const float* __restrict__ bias,
                                                    float* __restrict__ out, int n) {
    const int node = (blockIdx.x * blockDim.x + threadIdx.x) >> 6;
    if (node >= n) return;
    const int lane = threadIdx.x & 63;
    const int g = lane >> 4;
    const int r = lane & 15;
    const int beg = offs[node], end = offs[node + 1];
    const float erv = er[node];

    float a0 = 0.f, a1 = 0.f, a2 = 0.f, a3 = 0.f, l = 0.f;
    const int nb = (end - beg + 3) >> 2;
    int ci = beg + g; if (ci >= end) ci = end - 1;
    int s = csr[ci];
#pragma unroll 2
    for (int it = 0; it < nb; ++it) {
        const int ei = beg + it * 4 + g;
        const bool ok = ei < end;
        int nci = ei + 4; if (nci >= end) nci = end - 1;
        const int sn = csr[nci];
        float e = el[s] + erv;
        e = (e > 0.f) ? e : SLOPE * e;
        float p = __expf(fminf(e, 80.f));
        if (!ok) p = 0.f;
        const uint2 u = *(const uint2*)(Hf + (s << 6) + (r << 2));   // 8B fp16 x4
        const float h0 = __half2float(__ushort_as_half((unsigned short)(u.x & 0xFFFFu)));
        const float h1 = __half2float(__ushort_as_half((unsigned short)(u.x >> 16)));
        const float h2 = __half2float(__ushort_as_half((unsigned short)(u.y & 0xFFFFu)));
        const float h3 = __half2float(__ushort_as_half((unsigned short)(u.y >> 16)));
        l += p;
        a0 = fmaf(p, h0, a0);
        a1 = fmaf(p, h1, a1);
        a2 = fmaf(p, h2, a2);
        a3 = fmaf(p, h3, a3);
        s = sn;
    }

    a0 += __shfl_xor(a0, 16, 64); a0 += __shfl_xor(a0, 32, 64);
    a1 += __shfl_xor(a1, 16, 64); a1 += __shfl_xor(a1, 32, 64);
    a2 += __shfl_xor(a2, 16, 64); a2 += __shfl_xor(a2, 32, 64);
    a3 += __shfl_xor(a3, 16, 64); a3 += __shfl_xor(a3, 32, 64);
    l  += __shfl_xor(l, 16, 64);  l  += __shfl_xor(l, 32, 64);

    if (g == 0) {
        const float inv = (l > 0.f) ? 1.f / l : 0.f;
        const float4 b4 = *(const float4*)(bias + r * 4);
        *(float4*)(out + (node << 6) + (r << 2)) =
            make_float4(fmaf(a0, inv, b4.x), fmaf(a1, inv, b4.y),
                        fmaf(a2, inv, b4.z), fmaf(a3, inv, b4.w));
    }
}

// ---------------- launch ----------------

extern "C" void kernel_launch(void* const* d_in, const int* in_sizes, int n_in,
                              void* d_out, int out_size, void* d_ws, size_t ws_size,
                              hipStream_t stream) {
    const float* feat = (const float*)d_in[0];
    const int*   src  = (const int*)d_in[1];
    const int*   dst  = (const int*)d_in[2];
    const float* W1   = (const float*)d_in[3];
    const float* al1  = (const float*)d_in[4];
    const float* ar1  = (const float*)d_in[5];
    const float* b1   = (const float*)d_in[6];
    const float* W2   = (const float*)d_in[7];
    const float* al2  = (const float*)d_in[8];
    const float* ar2  = (const float*)d_in[9];
    const float* b2   = (const float*)d_in[10];
    float* out = (float*)d_out;

    const int IN = 256, HID = 64, OUT = 64, H1 = 4, H2 = 1;
    const int N = in_sizes[0] / IN;   // 50000
    const int E = in_sizes[1];        // 800000

    size_t off = 0;
    auto alloc = [&](size_t bytes) {
        void* p = (char*)d_ws + off;
        off += (bytes + 255) & ~(size_t)255;
        return p;
    };
    int*   deg    = (int*)alloc((size_t)N * 4);
    int*   offs   = (int*)alloc((size_t)(N + 1) * 4);
    int*   bsum   = (int*)alloc((size_t)256 * 4);
    int*   rank   = (int*)alloc((size_t)E * 4);
    int*   csr    = (int*)alloc((size_t)E * 4);
    unsigned short* h1   = (unsigned short*)alloc((size_t)N * H1 * HID * 2); // bf16
    unsigned short* wt1  = (unsigned short*)alloc((size_t)IN * H1 * HID * 2);// bf16 W1^T
    unsigned short* wt2  = (unsigned short*)alloc((size_t)H1 * HID * H2 * OUT * 2); // W2^T
    unsigned short* x2bf = (unsigned short*)alloc((size_t)N * H1 * HID * 2); // bf16 x2
    unsigned short* h2   = (unsigned short*)alloc((size_t)N * H2 * OUT * 2); // fp16
    float* el1    = (float*)alloc((size_t)N * H1 * 4);
    float* er1    = (float*)alloc((size_t)N * H1 * 4);
    float* el2    = (float*)alloc((size_t)N * H2 * 4);
    float* er2    = (float*)alloc((size_t)N * H2 * 4);
    (void)ws_size;

    hipMemsetAsync(deg, 0, (size_t)N * 4, stream);

    const int nb = (N + 255) / 256;   // 196 <= 256 (required by scan2_kernel)
    deg_kernel<<<(E + 255) / 256, 256, 0, stream>>>(dst, deg, rank, E);
    psum_kernel<<<nb, 256, 0, stream>>>(deg, bsum, N);
    scan2_kernel<<<nb, 256, 0, stream>>>(deg, bsum, offs, N);
    fill_kernel<<<(E + 255) / 256, 256, 0, stream>>>(src, dst, offs, rank, csr, E);

    // weight conversions (single dispatch)
    cvt_w_kernel<<<256, 256, 0, stream>>>(W1, W2, wt1, wt2);

    // ---- layer 1 ----
    {
        dim3 g((N + 127) / 128, 2);
        gemm1_mfma<<<g, 256, 0, stream>>>(feat, wt1, al1, ar1, h1, el1, er1, N);
    }
    aggr1_kernel<<<(N + 3) / 4, 256, 0, stream>>>(h1, el1, er1, offs, csr, b1, x2bf, N);
    // ---- layer 2 ----
    gemm2_mfma<<<(N + 127) / 128, 256, 0, stream>>>(x2bf, wt2, al2, ar2, h2, el2, er2, N);
    aggr2_kernel<<<(N + 3) / 4, 256, 0, stream>>>(h2, el2, er2, offs, csr, b2, out, N);
}

// Round 10
// 288.744 us; speedup vs baseline: 1.0586x; 1.0367x over previous
//
#include <hip/hip_runtime.h>
#include <hip/hip_bf16.h>
#include <hip/hip_fp16.h>
#include <math.h>

#define SLOPE 0.2f

typedef __attribute__((ext_vector_type(8))) short bf16x8;
typedef __attribute__((ext_vector_type(4))) float f32x4;

// bf16 helpers (manual, RNE)
__device__ inline unsigned short f2bf(float f) {
    unsigned u = __float_as_uint(f);
    u += 0x7FFF + ((u >> 16) & 1);
    return (unsigned short)(u >> 16);
}
__device__ inline float bf2f(unsigned short s) {
    return __uint_as_float(((unsigned)s) << 16);
}
// HW packed f32x2 -> bf16x2 (RNE), gfx950. lo = bf16(a), hi = bf16(b).
__device__ inline unsigned cvt_pk_bf16(float a, float b) {
    unsigned r;
    asm("v_cvt_pk_bf16_f32 %0, %1, %2" : "=v"(r) : "v"(a), "v"(b));
    return r;
}

// ---------------- CSR build (separate dispatches; R6: coop grid.sync ~100us
// per barrier on MI355X -> NEVER use cooperative launch for this) ----------

// rank[i] = arrival order of edge i at its dst node (doubles as cursor pass).
__global__ void deg_kernel(const int* __restrict__ dst, int* __restrict__ deg,
                           int* __restrict__ rank, int E) {
    int i = blockIdx.x * blockDim.x + threadIdx.x;
    if (i < E) rank[i] = atomicAdd(&deg[dst[i]], 1);
}

// Two-level device-wide exclusive scan (N <= 65536 so nb <= 256).
__global__ __launch_bounds__(256) void psum_kernel(const int* __restrict__ deg,
                                                   int* __restrict__ bsum, int n) {
    const int t = threadIdx.x;
    const int i = blockIdx.x * 256 + t;
    int v = (i < n) ? deg[i] : 0;
#pragma unroll
    for (int o = 1; o < 64; o <<= 1) v += __shfl_xor(v, o, 64);
    __shared__ int ws[4];
    if ((t & 63) == 0) ws[t >> 6] = v;
    __syncthreads();
    if (t == 0) bsum[blockIdx.x] = ws[0] + ws[1] + ws[2] + ws[3];
}

__global__ __launch_bounds__(256) void scan2_kernel(const int* __restrict__ deg,
                                                    const int* __restrict__ bsum,
                                                    int* __restrict__ offs, int n) {
    const int b = blockIdx.x, t = threadIdx.x;
    const int lane = t & 63, w = t >> 6;

    int contrib = (t < b) ? bsum[t] : 0;
#pragma unroll
    for (int o = 1; o < 64; o <<= 1) contrib += __shfl_xor(contrib, o, 64);
    __shared__ int wsum[4];
    if (lane == 0) wsum[w] = contrib;
    __syncthreads();
    const int base = wsum[0] + wsum[1] + wsum[2] + wsum[3];

    const int i = b * 256 + t;
    const int v = (i < n) ? deg[i] : 0;
    int incl = v;
#pragma unroll
    for (int o = 1; o < 64; o <<= 1) {
        const int u = __shfl_up(incl, o, 64);
        if (lane >= o) incl += u;
    }
    __shared__ int wtot[4];
    if (lane == 63) wtot[w] = incl;
    __syncthreads();
    int wbase = 0;
#pragma unroll
    for (int k = 0; k < 4; ++k)
        if (k < w) wbase += wtot[k];

    const int excl = base + wbase + incl - v;
    if (i < n) offs[i] = excl;
    if (i == n - 1) offs[n] = excl + v;
}

// Pure gather + scatter: no atomics (rank precomputed in deg_kernel).
__global__ void fill_kernel(const int* __restrict__ src, const int* __restrict__ dst,
                            const int* __restrict__ offs, const int* __restrict__ rank,
                            int* __restrict__ csr_src, int E) {
    int i = blockIdx.x * blockDim.x + threadIdx.x;
    if (i < E) {
        csr_src[offs[dst[i]] + rank[i]] = src[i];
    }
}

// ---------------- weight conversion (both layers, 1 dispatch) ----------------
// Wt[c][k] = bf16(W[k][c]). W1: 256x256, W2: 256x64.
__global__ void cvt_w_kernel(const float* __restrict__ W1, const float* __restrict__ W2,
                             unsigned short* __restrict__ Wt1,
                             unsigned short* __restrict__ Wt2) {
    const int k = blockIdx.x, c = threadIdx.x;
    Wt1[c * 256 + k] = f2bf(W1[k * 256 + c]);
    if (c < 64) Wt2[c * 256 + k] = f2bf(W2[k * 64 + c]);
}

// ---------------- layer-1 GEMM: LDS-tiled bf16 MFMA (full 256 outputs) -------
// One block = 128 nodes x ALL 256 output features: X is fetched+converted ONCE
// (vs twice with the old grid.y=2 split) and the k-loop/barrier count halves.
// LDS 55.3 KB, acc[16][2] -> ~170 VGPR, 2 blocks/CU.
__global__ __launch_bounds__(256) void gemm1_mfma(const float* __restrict__ Xf,
                                                  const unsigned short* __restrict__ Wt,
                                                  const float* __restrict__ AL,
                                                  const float* __restrict__ AR,
                                                  unsigned short* __restrict__ Hout,
                                                  float* __restrict__ el,
                                                  float* __restrict__ er, int n) {
    constexpr int LDR = 72;
    __shared__ __align__(16) unsigned short Xs[128 * LDR];
    __shared__ __align__(16) unsigned short Ws[256 * LDR];

    const int tid = threadIdx.x;
    const int wave = tid >> 6, lane = tid & 63;
    const int col16 = lane & 15, quad = lane >> 4;
    const int node0 = blockIdx.x * 128;

    f32x4 acc[16][2];
#pragma unroll
    for (int ft = 0; ft < 16; ++ft)
#pragma unroll
        for (int nt = 0; nt < 2; ++nt) acc[ft][nt] = (f32x4){0.f, 0.f, 0.f, 0.f};

    const int rr = tid >> 3;
    const int cc = (tid & 7) * 8;

    for (int k0 = 0; k0 < 256; k0 += 64) {
#pragma unroll
        for (int p = 0; p < 4; ++p) {
            const int row = rr + p * 32;
            int gx = node0 + row; if (gx >= n) gx = n - 1;
            const float4* xp = (const float4*)&Xf[(long long)gx * 256 + k0 + cc];
            const float4 a = xp[0];
            const float4 b = xp[1];
            uint4 pk;
            pk.x = cvt_pk_bf16(a.x, a.y);
            pk.y = cvt_pk_bf16(a.z, a.w);
            pk.z = cvt_pk_bf16(b.x, b.y);
            pk.w = cvt_pk_bf16(b.z, b.w);
            *(uint4*)&Xs[row * LDR + cc] = pk;
        }
#pragma unroll
        for (int p = 0; p < 8; ++p) {
            const int row = rr + p * 32;   // 0..255 output features
            *(bf16x8*)&Ws[row * LDR + cc] =
                *(const bf16x8*)&Wt[(long long)row * 256 + k0 + cc];
        }
        __syncthreads();
#pragma unroll
        for (int ks = 0; ks < 64; ks += 32) {
            bf16x8 bfrag[2];
#pragma unroll
            for (int nt = 0; nt < 2; ++nt)
                bfrag[nt] = *(const bf16x8*)&Xs[(wave * 32 + nt * 16 + col16) * LDR +
                                                ks + quad * 8];
#pragma unroll
            for (int ft = 0; ft < 16; ++ft) {
                const bf16x8 afrag =
                    *(const bf16x8*)&Ws[(ft * 16 + col16) * LDR + ks + quad * 8];
                acc[ft][0] = __builtin_amdgcn_mfma_f32_16x16x32_bf16(afrag, bfrag[0],
                                                                     acc[ft][0], 0, 0, 0);
                acc[ft][1] = __builtin_amdgcn_mfma_f32_16x16x32_bf16(afrag, bfrag[1],
                                                                     acc[ft][1], 0, 0, 0);
            }
        }
        __syncthreads();
    }

    float elp[2][4] = {{0.f}, {0.f}};
    float erp[2][4] = {{0.f}, {0.f}};
#pragma unroll
    for (int ft = 0; ft < 16; ++ft) {
        const int hb = ft >> 2;             // head 0..3
        float alw[4], arw[4];
#pragma unroll
        for (int r = 0; r < 4; ++r) {
            const int d = (ft & 3) * 16 + quad * 4 + r;
            alw[r] = AL[hb * 64 + d];
            arw[r] = AR[hb * 64 + d];
        }
#pragma unroll
        for (int nt = 0; nt < 2; ++nt) {
            const int node = node0 + wave * 32 + nt * 16 + col16;
            if (node < n) {
                uint2 pk;
                pk.x = cvt_pk_bf16(acc[ft][nt][0], acc[ft][nt][1]);
                pk.y = cvt_pk_bf16(acc[ft][nt][2], acc[ft][nt][3]);
                *(uint2*)&Hout[(long long)node * 256 + ft * 16 + quad * 4] = pk;
            }
#pragma unroll
            for (int r = 0; r < 4; ++r) {
                elp[nt][hb] = fmaf(acc[ft][nt][r], alw[r], elp[nt][hb]);
                erp[nt][hb] = fmaf(acc[ft][nt][r], arw[r], erp[nt][hb]);
            }
        }
    }
#pragma unroll
    for (int nt = 0; nt < 2; ++nt)
#pragma unroll
        for (int hb = 0; hb < 4; ++hb) {
            elp[nt][hb] += __shfl_xor(elp[nt][hb], 16, 64);
            elp[nt][hb] += __shfl_xor(elp[nt][hb], 32, 64);
            erp[nt][hb] += __shfl_xor(erp[nt][hb], 16, 64);
            erp[nt][hb] += __shfl_xor(erp[nt][hb], 32, 64);
        }
    if (quad == 0) {
#pragma unroll
        for (int nt = 0; nt < 2; ++nt) {
            const int node = node0 + wave * 32 + nt * 16 + col16;
            if (node < n) {
#pragma unroll
                for (int hb = 0; hb < 4; ++hb) {
                    el[node * 4 + hb] = elp[nt][hb];
                    er[node * 4 + hb] = erp[nt][hb];
                }
            }
        }
    }
}

// ---------------- layer-2 GEMM: LDS-tiled bf16 MFMA (M=64) ----------------
// Output h2 stored as fp16 (halves aggr2's gather bytes; 2^-11 rel err).
__global__ __launch_bounds__(256) void gemm2_mfma(const unsigned short* __restrict__ Xbf,
                                                  const unsigned short* __restrict__ Wt,
                                                  const float* __restrict__ AL,
                                                  const float* __restrict__ AR,
                                                  unsigned short* __restrict__ Hout,
                                                  float* __restrict__ el,
                                                  float* __restrict__ er, int n) {
    constexpr int LDR = 72;
    __shared__ __align__(16) unsigned short Xs[128 * LDR];
    __shared__ __align__(16) unsigned short Ws[64 * LDR];

    const int tid = threadIdx.x;
    const int wave = tid >> 6, lane = tid & 63;
    const int col16 = lane & 15, quad = lane >> 4;
    const int node0 = blockIdx.x * 128;

    f32x4 acc[4][2];
#pragma unroll
    for (int ft = 0; ft < 4; ++ft)
#pragma unroll
        for (int nt = 0; nt < 2; ++nt) acc[ft][nt] = (f32x4){0.f, 0.f, 0.f, 0.f};

    const int rr = tid >> 3;
    const int cc = (tid & 7) * 8;

    for (int k0 = 0; k0 < 256; k0 += 64) {
#pragma unroll
        for (int p = 0; p < 4; ++p) {
            const int row = rr + p * 32;
            int gx = node0 + row; if (gx >= n) gx = n - 1;
            *(bf16x8*)&Xs[row * LDR + cc] =
                *(const bf16x8*)&Xbf[(long long)gx * 256 + k0 + cc];
        }
#pragma unroll
        for (int p = 0; p < 2; ++p) {
            const int row = rr + p * 32;
            *(bf16x8*)&Ws[row * LDR + cc] =
                *(const bf16x8*)&Wt[(long long)row * 256 + k0 + cc];
        }
        __syncthreads();
#pragma unroll
        for (int ks = 0; ks < 64; ks += 32) {
            bf16x8 bfrag[2];
#pragma unroll
            for (int nt = 0; nt < 2; ++nt)
                bfrag[nt] = *(const bf16x8*)&Xs[(wave * 32 + nt * 16 + col16) * LDR +
                                                ks + quad * 8];
#pragma unroll
            for (int ft = 0; ft < 4; ++ft) {
                const bf16x8 afrag =
                    *(const bf16x8*)&Ws[(ft * 16 + col16) * LDR + ks + quad * 8];
                acc[ft][0] = __builtin_amdgcn_mfma_f32_16x16x32_bf16(afrag, bfrag[0],
                                                                     acc[ft][0], 0, 0, 0);
                acc[ft][1] = __builtin_amdgcn_mfma_f32_16x16x32_bf16(afrag, bfrag[1],
                                                                     acc[ft][1], 0, 0, 0);
            }
        }
        __syncthreads();
    }

    float elp[2] = {0.f, 0.f}, erp[2] = {0.f, 0.f};
#pragma unroll
    for (int ft = 0; ft < 4; ++ft) {
        float alw[4], arw[4];
#pragma unroll
        for (int r = 0; r < 4; ++r) {
            const int d = ft * 16 + quad * 4 + r;
            alw[r] = AL[d];
            arw[r] = AR[d];
        }
#pragma unroll
        for (int nt = 0; nt < 2; ++nt) {
            const int node = node0 + wave * 32 + nt * 16 + col16;
            if (node < n) {
                ushort4 pk;
                pk.x = __half_as_ushort(__float2half(acc[ft][nt][0]));
                pk.y = __half_as_ushort(__float2half(acc[ft][nt][1]));
                pk.z = __half_as_ushort(__float2half(acc[ft][nt][2]));
                pk.w = __half_as_ushort(__float2half(acc[ft][nt][3]));
                *(ushort4*)&Hout[(long long)node * 64 + ft * 16 + quad * 4] = pk;
            }
#pragma unroll
            for (int r = 0; r < 4; ++r) {
                elp[nt] = fmaf(acc[ft][nt][r], alw[r], elp[nt]);
                erp[nt] = fmaf(acc[ft][nt][r], arw[r], erp[nt]);
            }
        }
    }
#pragma unroll
    for (int nt = 0; nt < 2; ++nt) {
        elp[nt] += __shfl_xor(elp[nt], 16, 64);
        elp[nt] += __shfl_xor(elp[nt], 32, 64);
        erp[nt] += __shfl_xor(erp[nt], 16, 64);
        erp[nt] += __shfl_xor(erp[nt], 32, 64);
    }
    if (quad == 0) {
#pragma unroll
        for (int nt = 0; nt < 2; ++nt) {
            const int node = node0 + wave * 32 + nt * 16 + col16;
            if (node < n) {
                el[node] = elp[nt];
                er[node] = erp[nt];
            }
        }
    }
}

// ---------------- aggregation, 4 edges per wave-iteration ----------------
// Softmax numerators inline. One-iteration s-prefetch pipeline hides the
// csr->s->gather dependent chain. unroll 2 only (R4: unroll 4 kills occupancy).
__global__ __launch_bounds__(256) void aggr1_kernel(const unsigned short* __restrict__ Hf,
                                                    const float* __restrict__ el,
                                                    const float* __restrict__ er,
                                                    const int* __restrict__ offs,
                                                    const int* __restrict__ csr,
                                                    const float* __restrict__ bias,
                                                    unsigned short* __restrict__ out,
                                                    int n) {
    const int node = (blockIdx.x * blockDim.x + threadIdx.x) >> 6;
    if (node >= n) return;
    const int lane = threadIdx.x & 63;
    const int g = lane >> 4;       // edge subgroup
    const int r = lane & 15;       // feature slot: feats r*16 .. r*16+15
    const int h = r >> 2;          // head of this feature slot
    const int beg = offs[node], end = offs[node + 1];
    const float erv = er[node * 4 + h];

    float acc[16];
#pragma unroll
    for (int q = 0; q < 16; ++q) acc[q] = 0.f;
    float l = 0.f;

    const int nb = (end - beg + 3) >> 2;
    int ci = beg + g; if (ci >= end) ci = end - 1;
    int s = csr[ci];                       // prologue: first edge index
#pragma unroll 2
    for (int it = 0; it < nb; ++it) {
        const int ei = beg + it * 4 + g;
        const bool ok = ei < end;
        int nci = ei + 4; if (nci >= end) nci = end - 1;
        const int sn = csr[nci];           // prefetch next iteration's source
        float e = el[s * 4 + h] + erv;
        e = (e > 0.f) ? e : SLOPE * e;
        float p = __expf(fminf(e, 80.f));
        if (!ok) p = 0.f;
        const uint4* hp = (const uint4*)(Hf + (s << 8) + (r << 4));
        const uint4 u0 = hp[0];
        const uint4 u1 = hp[1];
        l += p;
        const unsigned uu[8] = {u0.x, u0.y, u0.z, u0.w, u1.x, u1.y, u1.z, u1.w};
#pragma unroll
        for (int q = 0; q < 8; ++q) {
            const float flo = __uint_as_float(uu[q] << 16);
            const float fhi = __uint_as_float(uu[q] & 0xFFFF0000u);
            acc[2 * q]     = fmaf(p, flo, acc[2 * q]);
            acc[2 * q + 1] = fmaf(p, fhi, acc[2 * q + 1]);
        }
        s = sn;
    }

#pragma unroll
    for (int q = 0; q < 16; ++q) {
        acc[q] += __shfl_xor(acc[q], 16, 64);
        acc[q] += __shfl_xor(acc[q], 32, 64);
    }
    l += __shfl_xor(l, 16, 64);
    l += __shfl_xor(l, 32, 64);

    if (g == 0) {
        const float inv = (l > 0.f) ? 1.f / l : 0.f;
        unsigned o[8];
#pragma unroll
        for (int q = 0; q < 8; ++q) {
            float v0 = acc[2 * q]     * inv + bias[r * 16 + 2 * q];
            float v1 = acc[2 * q + 1] * inv + bias[r * 16 + 2 * q + 1];
            v0 = (v0 > 0.f) ? v0 : expm1f(v0);   // ELU
            v1 = (v1 > 0.f) ? v1 : expm1f(v1);
            o[q] = cvt_pk_bf16(v0, v1);
        }
        uint4* op = (uint4*)(out + (node << 8) + (r << 4));
        op[0] = make_uint4(o[0], o[1], o[2], o[3]);
        op[1] = make_uint4(o[4], o[5], o[6], o[7]);
    }
}

// Layer 2: H=1, D=64 fp16. 8 lanes per edge (lane covers 8 feats, 1 uint4)
// -> 8 edges per wave-iteration: half the serial steps of the 16-lane form.
__global__ __launch_bounds__(256) void aggr2_kernel(const unsigned short* __restrict__ Hf,
                                                    const float* __restrict__ el,
                                                    const float* __restrict__ er,
                                                    const int* __restrict__ offs,
                                                    const int* __restrict__ csr,
                                                    const float* __restrict__ bias,
                                                    float* __restrict__ out, int n) {
    const int node = (blockIdx.x * blockDim.x + threadIdx.x) >> 6;
    if (node >= n) return;
    const int lane = threadIdx.x & 63;
    const int g = lane >> 3;       // edge subgroup 0..7
    const int r = lane & 7;        // feats r*8 .. r*8+7
    const int beg = offs[node], end = offs[node + 1];
    const float erv = er[node];

    float acc[8];
#pragma unroll
    for (int q = 0; q < 8; ++q) acc[q] = 0.f;
    float l = 0.f;

    const int nb = (end - beg + 7) >> 3;
    int ci = beg + g; if (ci >= end) ci = end - 1;
    int s = csr[ci];
#pragma unroll 2
    for (int it = 0; it < nb; ++it) {
        const int ei = beg + it * 8 + g;
        const bool ok = ei < end;
        int nci = ei + 8; if (nci >= end) nci = end - 1;
        const int sn = csr[nci];
        float e = el[s] + erv;
        e = (e > 0.f) ? e : SLOPE * e;
        float p = __expf(fminf(e, 80.f));
        if (!ok) p = 0.f;
        const uint4 u = *(const uint4*)(Hf + (s << 6) + (r << 3));   // 16B fp16 x8
        l += p;
        const unsigned uu[4] = {u.x, u.y, u.z, u.w};
#pragma unroll
        for (int q = 0; q < 4; ++q) {
            const float hlo = __half2float(__ushort_as_half((unsigned short)(uu[q] & 0xFFFFu)));
            const float hhi = __half2float(__ushort_as_half((unsigned short)(uu[q] >> 16)));
            acc[2 * q]     = fmaf(p, hlo, acc[2 * q]);
            acc[2 * q + 1] = fmaf(p, hhi, acc[2 * q + 1]);
        }
        s = sn;
    }

#pragma unroll
    for (int q = 0; q < 8; ++q) {
        acc[q] += __shfl_xor(acc[q], 8, 64);
        acc[q] += __shfl_xor(acc[q], 16, 64);
        acc[q] += __shfl_xor(acc[q], 32, 64);
    }
    l += __shfl_xor(l, 8, 64);
    l += __shfl_xor(l, 16, 64);
    l += __shfl_xor(l, 32, 64);

    if (g == 0) {
        const float inv = (l > 0.f) ? 1.f / l : 0.f;
        const float4 b0 = *(const float4*)(bias + r * 8);
        const float4 b1 = *(const float4*)(bias + r * 8 + 4);
        float* op = out + (node << 6) + (r << 3);
        *(float4*)op = make_float4(fmaf(acc[0], inv, b0.x), fmaf(acc[1], inv, b0.y),
                                   fmaf(acc[2], inv, b0.z), fmaf(acc[3], inv, b0.w));
        *(float4*)(op + 4) = make_float4(fmaf(acc[4], inv, b1.x), fmaf(acc[5], inv, b1.y),
                                         fmaf(acc[6], inv, b1.z), fmaf(acc[7], inv, b1.w));
    }
}

// ---------------- launch ----------------

extern "C" void kernel_launch(void* const* d_in, const int* in_sizes, int n_in,
                              void* d_out, int out_size, void* d_ws, size_t ws_size,
                              hipStream_t stream) {
    const float* feat = (const float*)d_in[0];
    const int*   src  = (const int*)d_in[1];
    const int*   dst  = (const int*)d_in[2];
    const float* W1   = (const float*)d_in[3];
    const float* al1  = (const float*)d_in[4];
    const float* ar1  = (const float*)d_in[5];
    const float* b1   = (const float*)d_in[6];
    const float* W2   = (const float*)d_in[7];
    const float* al2  = (const float*)d_in[8];
    const float* ar2  = (const float*)d_in[9];
    const float* b2   = (const float*)d_in[10];
    float* out = (float*)d_out;

    const int IN = 256, HID = 64, OUT = 64, H1 = 4, H2 = 1;
    const int N = in_sizes[0] / IN;   // 50000
    const int E = in_sizes[1];        // 800000

    size_t off = 0;
    auto alloc = [&](size_t bytes) {
        void* p = (char*)d_ws + off;
        off += (bytes + 255) & ~(size_t)255;
        return p;
    };
    int*   deg    = (int*)alloc((size_t)N * 4);
    int*   offs   = (int*)alloc((size_t)(N + 1) * 4);
    int*   bsum   = (int*)alloc((size_t)256 * 4);
    int*   rank   = (int*)alloc((size_t)E * 4);
    int*   csr    = (int*)alloc((size_t)E * 4);
    unsigned short* h1   = (unsigned short*)alloc((size_t)N * H1 * HID * 2); // bf16
    unsigned short* wt1  = (unsigned short*)alloc((size_t)IN * H1 * HID * 2);// bf16 W1^T
    unsigned short* wt2  = (unsigned short*)alloc((size_t)H1 * HID * H2 * OUT * 2); // W2^T
    unsigned short* x2bf = (unsigned short*)alloc((size_t)N * H1 * HID * 2); // bf16 x2
    unsigned short* h2   = (unsigned short*)alloc((size_t)N * H2 * OUT * 2); // fp16
    float* el1    = (float*)alloc((size_t)N * H1 * 4);
    float* er1    = (float*)alloc((size_t)N * H1 * 4);
    float* el2    = (float*)alloc((size_t)N * H2 * 4);
    float* er2    = (float*)alloc((size_t)N * H2 * 4);
    (void)ws_size;

    hipMemsetAsync(deg, 0, (size_t)N * 4, stream);

    const int nb = (N + 255) / 256;   // 196 <= 256 (required by scan2_kernel)
    deg_kernel<<<(E + 255) / 256, 256, 0, stream>>>(dst, deg, rank, E);
    psum_kernel<<<nb, 256, 0, stream>>>(deg, bsum, N);
    scan2_kernel<<<nb, 256, 0, stream>>>(deg, bsum, offs, N);
    fill_kernel<<<(E + 255) / 256, 256, 0, stream>>>(src, dst, offs, rank, csr, E);

    // weight conversions (single dispatch)
    cvt_w_kernel<<<256, 256, 0, stream>>>(W1, W2, wt1, wt2);

    // ---- layer 1 ----
    gemm1_mfma<<<(N + 127) / 128, 256, 0, stream>>>(feat, wt1, al1, ar1, h1, el1, er1, N);
    aggr1_kernel<<<(N + 3) / 4, 256, 0, stream>>>(h1, el1, er1, offs, csr, b1, x2bf, N);
    // ---- layer 2 ----
    gemm2_mfma<<<(N + 127) / 128, 256, 0, stream>>>(x2bf, wt2, al2, ar2, h2, el2, er2, N);
    aggr2_kernel<<<(N + 3) / 4, 256, 0, stream>>>(h2, el2, er2, offs, csr, b2, out, N);
}

// Round 11
// 282.666 us; speedup vs baseline: 1.0814x; 1.0215x over previous
//
#include <hip/hip_runtime.h>
#include <hip/hip_bf16.h>
#include <hip/hip_fp16.h>
#include <math.h>

#define SLOPE 0.2f

typedef __attribute__((ext_vector_type(8))) short bf16x8;
typedef __attribute__((ext_vector_type(4))) float f32x4;

// bf16 helpers (manual, RNE)
__device__ inline unsigned short f2bf(float f) {
    unsigned u = __float_as_uint(f);
    u += 0x7FFF + ((u >> 16) & 1);
    return (unsigned short)(u >> 16);
}
__device__ inline float bf2f(unsigned short s) {
    return __uint_as_float(((unsigned)s) << 16);
}
// HW packed f32x2 -> bf16x2 (RNE), gfx950. lo = bf16(a), hi = bf16(b).
__device__ inline unsigned cvt_pk_bf16(float a, float b) {
    unsigned r;
    asm("v_cvt_pk_bf16_f32 %0, %1, %2" : "=v"(r) : "v"(a), "v"(b));
    return r;
}

// ---------------- CSR build (separate dispatches; R6: coop grid.sync ~100us
// per barrier on MI355X -> NEVER use cooperative launch for this) ----------

// Fused: cvt_w (blocks 0..255) || deg+rank (remaining blocks). Independent work
// in ONE dispatch -> runs concurrently (same-stream kernels serialize).
__global__ void deg_cvtw_kernel(const int* __restrict__ dst, int* __restrict__ deg,
                                int* __restrict__ rank, int E,
                                const float* __restrict__ W1,
                                const float* __restrict__ W2,
                                unsigned short* __restrict__ Wt1,
                                unsigned short* __restrict__ Wt2) {
    if (blockIdx.x < 256) {
        const int k = blockIdx.x, c = threadIdx.x;
        Wt1[c * 256 + k] = f2bf(W1[k * 256 + c]);
        if (c < 64) Wt2[c * 256 + k] = f2bf(W2[k * 64 + c]);
    } else {
        const int i = (blockIdx.x - 256) * blockDim.x + threadIdx.x;
        if (i < E) rank[i] = atomicAdd(&deg[dst[i]], 1);
    }
}

// Two-level device-wide exclusive scan (N <= 65536 so nb <= 256).
__global__ __launch_bounds__(256) void psum_kernel(const int* __restrict__ deg,
                                                   int* __restrict__ bsum, int n) {
    const int t = threadIdx.x;
    const int i = blockIdx.x * 256 + t;
    int v = (i < n) ? deg[i] : 0;
#pragma unroll
    for (int o = 1; o < 64; o <<= 1) v += __shfl_xor(v, o, 64);
    __shared__ int ws[4];
    if ((t & 63) == 0) ws[t >> 6] = v;
    __syncthreads();
    if (t == 0) bsum[blockIdx.x] = ws[0] + ws[1] + ws[2] + ws[3];
}

__global__ __launch_bounds__(256) void scan2_kernel(const int* __restrict__ deg,
                                                    const int* __restrict__ bsum,
                                                    int* __restrict__ offs, int n) {
    const int b = blockIdx.x, t = threadIdx.x;
    const int lane = t & 63, w = t >> 6;

    int contrib = (t < b) ? bsum[t] : 0;
#pragma unroll
    for (int o = 1; o < 64; o <<= 1) contrib += __shfl_xor(contrib, o, 64);
    __shared__ int wsum[4];
    if (lane == 0) wsum[w] = contrib;
    __syncthreads();
    const int base = wsum[0] + wsum[1] + wsum[2] + wsum[3];

    const int i = b * 256 + t;
    const int v = (i < n) ? deg[i] : 0;
    int incl = v;
#pragma unroll
    for (int o = 1; o < 64; o <<= 1) {
        const int u = __shfl_up(incl, o, 64);
        if (lane >= o) incl += u;
    }
    __shared__ int wtot[4];
    if (lane == 63) wtot[w] = incl;
    __syncthreads();
    int wbase = 0;
#pragma unroll
    for (int k = 0; k < 4; ++k)
        if (k < w) wbase += wtot[k];

    const int excl = base + wbase + incl - v;
    if (i < n) offs[i] = excl;
    if (i == n - 1) offs[n] = excl + v;
}

// ---------------- fused fill || layer-1 GEMM -------------------------------
// gemm1 blocks come FIRST (claim CUs early, long-running); fill blocks (pure
// gather+scatter, rank precomputed, no atomics) stream in alongside and their
// latency-bound time hides completely under the GEMM.
__global__ __launch_bounds__(256) void gemm1_fill(const float* __restrict__ Xf,
                                                  const unsigned short* __restrict__ Wt,
                                                  const float* __restrict__ AL,
                                                  const float* __restrict__ AR,
                                                  unsigned short* __restrict__ Hout,
                                                  float* __restrict__ el,
                                                  float* __restrict__ er, int n, int GB,
                                                  const int* __restrict__ src,
                                                  const int* __restrict__ dst,
                                                  const int* __restrict__ offs,
                                                  const int* __restrict__ rank,
                                                  int* __restrict__ csr_src, int E) {
    constexpr int LDR = 72;
    __shared__ __align__(16) unsigned short Xs[128 * LDR];
    __shared__ __align__(16) unsigned short Ws[256 * LDR];

    if (blockIdx.x >= GB) {
        // ---- fill branch ----
        const int i = (blockIdx.x - GB) * blockDim.x + threadIdx.x;
        if (i < E) csr_src[offs[dst[i]] + rank[i]] = src[i];
        return;
    }

    // ---- gemm1 branch: 128 nodes x ALL 256 outputs, X fetched+cvt ONCE ----
    const int tid = threadIdx.x;
    const int wave = tid >> 6, lane = tid & 63;
    const int col16 = lane & 15, quad = lane >> 4;
    const int node0 = blockIdx.x * 128;

    f32x4 acc[16][2];
#pragma unroll
    for (int ft = 0; ft < 16; ++ft)
#pragma unroll
        for (int nt = 0; nt < 2; ++nt) acc[ft][nt] = (f32x4){0.f, 0.f, 0.f, 0.f};

    const int rr = tid >> 3;
    const int cc = (tid & 7) * 8;

    for (int k0 = 0; k0 < 256; k0 += 64) {
#pragma unroll
        for (int p = 0; p < 4; ++p) {
            const int row = rr + p * 32;
            int gx = node0 + row; if (gx >= n) gx = n - 1;
            const float4* xp = (const float4*)&Xf[(long long)gx * 256 + k0 + cc];
            const float4 a = xp[0];
            const float4 b = xp[1];
            uint4 pk;
            pk.x = cvt_pk_bf16(a.x, a.y);
            pk.y = cvt_pk_bf16(a.z, a.w);
            pk.z = cvt_pk_bf16(b.x, b.y);
            pk.w = cvt_pk_bf16(b.z, b.w);
            *(uint4*)&Xs[row * LDR + cc] = pk;
        }
#pragma unroll
        for (int p = 0; p < 8; ++p) {
            const int row = rr + p * 32;   // 0..255 output features
            *(bf16x8*)&Ws[row * LDR + cc] =
                *(const bf16x8*)&Wt[(long long)row * 256 + k0 + cc];
        }
        __syncthreads();
#pragma unroll
        for (int ks = 0; ks < 64; ks += 32) {
            bf16x8 bfrag[2];
#pragma unroll
            for (int nt = 0; nt < 2; ++nt)
                bfrag[nt] = *(const bf16x8*)&Xs[(wave * 32 + nt * 16 + col16) * LDR +
                                                ks + quad * 8];
#pragma unroll
            for (int ft = 0; ft < 16; ++ft) {
                const bf16x8 afrag =
                    *(const bf16x8*)&Ws[(ft * 16 + col16) * LDR + ks + quad * 8];
                acc[ft][0] = __builtin_amdgcn_mfma_f32_16x16x32_bf16(afrag, bfrag[0],
                                                                     acc[ft][0], 0, 0, 0);
                acc[ft][1] = __builtin_amdgcn_mfma_f32_16x16x32_bf16(afrag, bfrag[1],
                                                                     acc[ft][1], 0, 0, 0);
            }
        }
        __syncthreads();
    }

    float elp[2][4] = {{0.f}, {0.f}};
    float erp[2][4] = {{0.f}, {0.f}};
#pragma unroll
    for (int ft = 0; ft < 16; ++ft) {
        const int hb = ft >> 2;             // head 0..3
        float alw[4], arw[4];
#pragma unroll
        for (int r = 0; r < 4; ++r) {
            const int d = (ft & 3) * 16 + quad * 4 + r;
            alw[r] = AL[hb * 64 + d];
            arw[r] = AR[hb * 64 + d];
        }
#pragma unroll
        for (int nt = 0; nt < 2; ++nt) {
            const int node = node0 + wave * 32 + nt * 16 + col16;
            if (node < n) {
                uint2 pk;
                pk.x = cvt_pk_bf16(acc[ft][nt][0], acc[ft][nt][1]);
                pk.y = cvt_pk_bf16(acc[ft][nt][2], acc[ft][nt][3]);
                *(uint2*)&Hout[(long long)node * 256 + ft * 16 + quad * 4] = pk;
            }
#pragma unroll
            for (int r = 0; r < 4; ++r) {
                elp[nt][hb] = fmaf(acc[ft][nt][r], alw[r], elp[nt][hb]);
                erp[nt][hb] = fmaf(acc[ft][nt][r], arw[r], erp[nt][hb]);
            }
        }
    }
#pragma unroll
    for (int nt = 0; nt < 2; ++nt)
#pragma unroll
        for (int hb = 0; hb < 4; ++hb) {
            elp[nt][hb] += __shfl_xor(elp[nt][hb], 16, 64);
            elp[nt][hb] += __shfl_xor(elp[nt][hb], 32, 64);
            erp[nt][hb] += __shfl_xor(erp[nt][hb], 16, 64);
            erp[nt][hb] += __shfl_xor(erp[nt][hb], 32, 64);
        }
    if (quad == 0) {
#pragma unroll
        for (int nt = 0; nt < 2; ++nt) {
            const int node = node0 + wave * 32 + nt * 16 + col16;
            if (node < n) {
#pragma unroll
                for (int hb = 0; hb < 4; ++hb) {
                    el[node * 4 + hb] = elp[nt][hb];
                    er[node * 4 + hb] = erp[nt][hb];
                }
            }
        }
    }
}

// ---------------- layer-2 GEMM: LDS-tiled bf16 MFMA (M=64) ----------------
// Output h2 stored as fp16 (halves aggr2's gather bytes; 2^-11 rel err).
__global__ __launch_bounds__(256) void gemm2_mfma(const unsigned short* __restrict__ Xbf,
                                                  const unsigned short* __restrict__ Wt,
                                                  const float* __restrict__ AL,
                                                  const float* __restrict__ AR,
                                                  unsigned short* __restrict__ Hout,
                                                  float* __restrict__ el,
                                                  float* __restrict__ er, int n) {
    constexpr int LDR = 72;
    __shared__ __align__(16) unsigned short Xs[128 * LDR];
    __shared__ __align__(16) unsigned short Ws[64 * LDR];

    const int tid = threadIdx.x;
    const int wave = tid >> 6, lane = tid & 63;
    const int col16 = lane & 15, quad = lane >> 4;
    const int node0 = blockIdx.x * 128;

    f32x4 acc[4][2];
#pragma unroll
    for (int ft = 0; ft < 4; ++ft)
#pragma unroll
        for (int nt = 0; nt < 2; ++nt) acc[ft][nt] = (f32x4){0.f, 0.f, 0.f, 0.f};

    const int rr = tid >> 3;
    const int cc = (tid & 7) * 8;

    for (int k0 = 0; k0 < 256; k0 += 64) {
#pragma unroll
        for (int p = 0; p < 4; ++p) {
            const int row = rr + p * 32;
            int gx = node0 + row; if (gx >= n) gx = n - 1;
            *(bf16x8*)&Xs[row * LDR + cc] =
                *(const bf16x8*)&Xbf[(long long)gx * 256 + k0 + cc];
        }
#pragma unroll
        for (int p = 0; p < 2; ++p) {
            const int row = rr + p * 32;
            *(bf16x8*)&Ws[row * LDR + cc] =
                *(const bf16x8*)&Wt[(long long)row * 256 + k0 + cc];
        }
        __syncthreads();
#pragma unroll
        for (int ks = 0; ks < 64; ks += 32) {
            bf16x8 bfrag[2];
#pragma unroll
            for (int nt = 0; nt < 2; ++nt)
                bfrag[nt] = *(const bf16x8*)&Xs[(wave * 32 + nt * 16 + col16) * LDR +
                                                ks + quad * 8];
#pragma unroll
            for (int ft = 0; ft < 4; ++ft) {
                const bf16x8 afrag =
                    *(const bf16x8*)&Ws[(ft * 16 + col16) * LDR + ks + quad * 8];
                acc[ft][0] = __builtin_amdgcn_mfma_f32_16x16x32_bf16(afrag, bfrag[0],
                                                                     acc[ft][0], 0, 0, 0);
                acc[ft][1] = __builtin_amdgcn_mfma_f32_16x16x32_bf16(afrag, bfrag[1],
                                                                     acc[ft][1], 0, 0, 0);
            }
        }
        __syncthreads();
    }

    float elp[2] = {0.f, 0.f}, erp[2] = {0.f, 0.f};
#pragma unroll
    for (int ft = 0; ft < 4; ++ft) {
        float alw[4], arw[4];
#pragma unroll
        for (int r = 0; r < 4; ++r) {
            const int d = ft * 16 + quad * 4 + r;
            alw[r] = AL[d];
            arw[r] = AR[d];
        }
#pragma unroll
        for (int nt = 0; nt < 2; ++nt) {
            const int node = node0 + wave * 32 + nt * 16 + col16;
            if (node < n) {
                ushort4 pk;
                pk.x = __half_as_ushort(__float2half(acc[ft][nt][0]));
                pk.y = __half_as_ushort(__float2half(acc[ft][nt][1]));
                pk.z = __half_as_ushort(__float2half(acc[ft][nt][2]));
                pk.w = __half_as_ushort(__float2half(acc[ft][nt][3]));
                *(ushort4*)&Hout[(long long)node * 64 + ft * 16 + quad * 4] = pk;
            }
#pragma unroll
            for (int r = 0; r < 4; ++r) {
                elp[nt] = fmaf(acc[ft][nt][r], alw[r], elp[nt]);
                erp[nt] = fmaf(acc[ft][nt][r], arw[r], erp[nt]);
            }
        }
    }
#pragma unroll
    for (int nt = 0; nt < 2; ++nt) {
        elp[nt] += __shfl_xor(elp[nt], 16, 64);
        elp[nt] += __shfl_xor(elp[nt], 32, 64);
        erp[nt] += __shfl_xor(erp[nt], 16, 64);
        erp[nt] += __shfl_xor(erp[nt], 32, 64);
    }
    if (quad == 0) {
#pragma unroll
        for (int nt = 0; nt < 2; ++nt) {
            const int node = node0 + wave * 32 + nt * 16 + col16;
            if (node < n) {
                el[node] = elp[nt];
                er[node] = erp[nt];
            }
        }
    }
}

// ---------------- aggregation, 4 edges per wave-iteration ----------------
// Softmax numerators inline. One-iteration s-prefetch pipeline hides the
// csr->s->gather dependent chain. unroll 2 only (R4: unroll 4 kills occupancy).
__global__ __launch_bounds__(256) void aggr1_kernel(const unsigned short* __restrict__ Hf,
                                                    const float* __restrict__ el,
                                                    const float* __restrict__ er,
                                                    const int* __restrict__ offs,
                                                    const int* __restrict__ csr,
                                                    const float* __restrict__ bias,
                                                    unsigned short* __restrict__ out,
                                                    int n) {
    const int node = (blockIdx.x * blockDim.x + threadIdx.x) >> 6;
    if (node >= n) return;
    const int lane = threadIdx.x & 63;
    const int g = lane >> 4;       // edge subgroup
    const int r = lane & 15;       // feature slot: feats r*16 .. r*16+15
    const int h = r >> 2;          // head of this feature slot
    const int beg = offs[node], end = offs[node + 1];
    const float erv = er[node * 4 + h];

    float acc[16];
#pragma unroll
    for (int q = 0; q < 16; ++q) acc[q] = 0.f;
    float l = 0.f;

    const int nb = (end - beg + 3) >> 2;
    int ci = beg + g; if (ci >= end) ci = end - 1;
    int s = csr[ci];                       // prologue: first edge index
#pragma unroll 2
    for (int it = 0; it < nb; ++it) {
        const int ei = beg + it * 4 + g;
        const bool ok = ei < end;
        int nci = ei + 4; if (nci >= end) nci = end - 1;
        const int sn = csr[nci];           // prefetch next iteration's source
        float e = el[s * 4 + h] + erv;
        e = (e > 0.f) ? e : SLOPE * e;
        float p = __expf(fminf(e, 80.f));
        if (!ok) p = 0.f;
        const uint4* hp = (const uint4*)(Hf + (s << 8) + (r << 4));
        const uint4 u0 = hp[0];
        const uint4 u1 = hp[1];
        l += p;
        const unsigned uu[8] = {u0.x, u0.y, u0.z, u0.w, u1.x, u1.y, u1.z, u1.w};
#pragma unroll
        for (int q = 0; q < 8; ++q) {
            const float flo = __uint_as_float(uu[q] << 16);
            const float fhi = __uint_as_float(uu[q] & 0xFFFF0000u);
            acc[2 * q]     = fmaf(p, flo, acc[2 * q]);
            acc[2 * q + 1] = fmaf(p, fhi, acc[2 * q + 1]);
        }
        s = sn;
    }

#pragma unroll
    for (int q = 0; q < 16; ++q) {
        acc[q] += __shfl_xor(acc[q], 16, 64);
        acc[q] += __shfl_xor(acc[q], 32, 64);
    }
    l += __shfl_xor(l, 16, 64);
    l += __shfl_xor(l, 32, 64);

    if (g == 0) {
        const float inv = (l > 0.f) ? 1.f / l : 0.f;
        unsigned o[8];
#pragma unroll
        for (int q = 0; q < 8; ++q) {
            float v0 = acc[2 * q]     * inv + bias[r * 16 + 2 * q];
            float v1 = acc[2 * q + 1] * inv + bias[r * 16 + 2 * q + 1];
            v0 = (v0 > 0.f) ? v0 : expm1f(v0);   // ELU
            v1 = (v1 > 0.f) ? v1 : expm1f(v1);
            o[q] = cvt_pk_bf16(v0, v1);
        }
        uint4* op = (uint4*)(out + (node << 8) + (r << 4));
        op[0] = make_uint4(o[0], o[1], o[2], o[3]);
        op[1] = make_uint4(o[4], o[5], o[6], o[7]);
    }
}

// Layer 2: H=1, D=64 fp16. 8 lanes per edge (lane covers 8 feats, 1 uint4)
// -> 8 edges per wave-iteration: half the serial steps of the 16-lane form.
__global__ __launch_bounds__(256) void aggr2_kernel(const unsigned short* __restrict__ Hf,
                                                    const float* __restrict__ el,
                                                    const float* __restrict__ er,
                                                    const int* __restrict__ offs,
                                                    const int* __restrict__ csr,
                                                    const float* __restrict__ bias,
                                                    float* __restrict__ out, int n) {
    const int node = (blockIdx.x * blockDim.x + threadIdx.x) >> 6;
    if (node >= n) return;
    const int lane = threadIdx.x & 63;
    const int g = lane >> 3;       // edge subgroup 0..7
    const int r = lane & 7;        // feats r*8 .. r*8+7
    const int beg = offs[node], end = offs[node + 1];
    const float erv = er[node];

    float acc[8];
#pragma unroll
    for (int q = 0; q < 8; ++q) acc[q] = 0.f;
    float l = 0.f;

    const int nb = (end - beg + 7) >> 3;
    int ci = beg + g; if (ci >= end) ci = end - 1;
    int s = csr[ci];
#pragma unroll 2
    for (int it = 0; it < nb; ++it) {
        const int ei = beg + it * 8 + g;
        const bool ok = ei < end;
        int nci = ei + 8; if (nci >= end) nci = end - 1;
        const int sn = csr[nci];
        float e = el[s] + erv;
        e = (e > 0.f) ? e : SLOPE * e;
        float p = __expf(fminf(e, 80.f));
        if (!ok) p = 0.f;
        const uint4 u = *(const uint4*)(Hf + (s << 6) + (r << 3));   // 16B fp16 x8
        l += p;
        const unsigned uu[4] = {u.x, u.y, u.z, u.w};
#pragma unroll
        for (int q = 0; q < 4; ++q) {
            const float hlo = __half2float(__ushort_as_half((unsigned short)(uu[q] & 0xFFFFu)));
            const float hhi = __half2float(__ushort_as_half((unsigned short)(uu[q] >> 16)));
            acc[2 * q]     = fmaf(p, hlo, acc[2 * q]);
            acc[2 * q + 1] = fmaf(p, hhi, acc[2 * q + 1]);
        }
        s = sn;
    }

#pragma unroll
    for (int q = 0; q < 8; ++q) {
        acc[q] += __shfl_xor(acc[q], 8, 64);
        acc[q] += __shfl_xor(acc[q], 16, 64);
        acc[q] += __shfl_xor(acc[q], 32, 64);
    }
    l += __shfl_xor(l, 8, 64);
    l += __shfl_xor(l, 16, 64);
    l += __shfl_xor(l, 32, 64);

    if (g == 0) {
        const float inv = (l > 0.f) ? 1.f / l : 0.f;
        const float4 b0 = *(const float4*)(bias + r * 8);
        const float4 b1 = *(const float4*)(bias + r * 8 + 4);
        float* op = out + (node << 6) + (r << 3);
        *(float4*)op = make_float4(fmaf(acc[0], inv, b0.x), fmaf(acc[1], inv, b0.y),
                                   fmaf(acc[2], inv, b0.z), fmaf(acc[3], inv, b0.w));
        *(float4*)(op + 4) = make_float4(fmaf(acc[4], inv, b1.x), fmaf(acc[5], inv, b1.y),
                                         fmaf(acc[6], inv, b1.z), fmaf(acc[7], inv, b1.w));
    }
}

// ---------------- launch ----------------

extern "C" void kernel_launch(void* const* d_in, const int* in_sizes, int n_in,
                              void* d_out, int out_size, void* d_ws, size_t ws_size,
                              hipStream_t stream) {
    const float* feat = (const float*)d_in[0];
    const int*   src  = (const int*)d_in[1];
    const int*   dst  = (const int*)d_in[2];
    const float* W1   = (const float*)d_in[3];
    const float* al1  = (const float*)d_in[4];
    const float* ar1  = (const float*)d_in[5];
    const float* b1   = (const float*)d_in[6];
    const float* W2   = (const float*)d_in[7];
    const float* al2  = (const float*)d_in[8];
    const float* ar2  = (const float*)d_in[9];
    const float* b2   = (const float*)d_in[10];
    float* out = (float*)d_out;

    const int IN = 256, HID = 64, OUT = 64, H1 = 4, H2 = 1;
    const int N = in_sizes[0] / IN;   // 50000
    const int E = in_sizes[1];        // 800000

    size_t off = 0;
    auto alloc = [&](size_t bytes) {
        void* p = (char*)d_ws + off;
        off += (bytes + 255) & ~(size_t)255;
        return p;
    };
    int*   deg    = (int*)alloc((size_t)N * 4);
    int*   offs   = (int*)alloc((size_t)(N + 1) * 4);
    int*   bsum   = (int*)alloc((size_t)256 * 4);
    int*   rank   = (int*)alloc((size_t)E * 4);
    int*   csr    = (int*)alloc((size_t)E * 4);
    unsigned short* h1   = (unsigned short*)alloc((size_t)N * H1 * HID * 2); // bf16
    unsigned short* wt1  = (unsigned short*)alloc((size_t)IN * H1 * HID * 2);// bf16 W1^T
    unsigned short* wt2  = (unsigned short*)alloc((size_t)H1 * HID * H2 * OUT * 2); // W2^T
    unsigned short* x2bf = (unsigned short*)alloc((size_t)N * H1 * HID * 2); // bf16 x2
    unsigned short* h2   = (unsigned short*)alloc((size_t)N * H2 * OUT * 2); // fp16
    float* el1    = (float*)alloc((size_t)N * H1 * 4);
    float* er1    = (float*)alloc((size_t)N * H1 * 4);
    float* el2    = (float*)alloc((size_t)N * H2 * 4);
    float* er2    = (float*)alloc((size_t)N * H2 * 4);
    (void)ws_size;

    hipMemsetAsync(deg, 0, (size_t)N * 4, stream);

    const int nb = (N + 255) / 256;   // 196 <= 256 (required by scan2_kernel)
    const int eb = (E + 255) / 256;   // 3125
    const int GB = (N + 127) / 128;   // 391 gemm1 blocks

    // deg+rank || cvt_w in one dispatch
    deg_cvtw_kernel<<<256 + eb, 256, 0, stream>>>(dst, deg, rank, E, W1, W2, wt1, wt2);
    psum_kernel<<<nb, 256, 0, stream>>>(deg, bsum, N);
    scan2_kernel<<<nb, 256, 0, stream>>>(deg, bsum, offs, N);

    // gemm1 (blocks 0..GB-1) || fill (blocks GB..GB+eb-1) in one dispatch
    gemm1_fill<<<GB + eb, 256, 0, stream>>>(feat, wt1, al1, ar1, h1, el1, er1, N, GB,
                                            src, dst, offs, rank, csr, E);

    aggr1_kernel<<<(N + 3) / 4, 256, 0, stream>>>(h1, el1, er1, offs, csr, b1, x2bf, N);
    // ---- layer 2 ----
    gemm2_mfma<<<(N + 127) / 128, 256, 0, stream>>>(x2bf, wt2, al2, ar2, h2, el2, er2, N);
    aggr2_kernel<<<(N + 3) / 4, 256, 0, stream>>>(h2, el2, er2, offs, csr, b2, out, N);
}